// Round 2
// baseline (2662.716 us; speedup 1.0000x reference)
//
#include <hip/hip_runtime.h>

typedef unsigned short u16;
typedef unsigned int u32;
using bf16x8 = __attribute__((ext_vector_type(8))) short;
using f32x4 = __attribute__((ext_vector_type(4))) float;

constexpr int kL = 8192;
constexpr int kDIM = 256;
constexpr int kDI = 512;
constexpr int kNB = 8;
constexpr float kEPS = 1e-3f;

__device__ __forceinline__ u16 f2b(float f) {
  u32 x = __builtin_bit_cast(u32, f);
  x += 0x7fffu + ((x >> 16) & 1u);
  return (u16)(x >> 16);
}
__device__ __forceinline__ float b2f(u16 u) {
  return __builtin_bit_cast(float, (u32)u << 16);
}
__device__ __forceinline__ float sigm(float x) { return 1.f / (1.f + __expf(-x)); }

__device__ __forceinline__ void async_cp16(const void* g, void* l) {
  __builtin_amdgcn_global_load_lds((const __attribute__((address_space(1))) u32*)g,
                                   (__attribute__((address_space(3))) u32*)l, 16, 0, 0);
}

// ---------------- weight conversion: many segments in one kernel ----------------
struct CvtDescs {
  const float* s[22];
  u16* d[22];
  int n[22];
};
__global__ __launch_bounds__(256) void cvt_multi_k(CvtDescs dd) {
  const int seg = blockIdx.y;
  const float* src = dd.s[seg];
  u16* dst = dd.d[seg];
  const int n = dd.n[seg];
  for (int i = blockIdx.x * 256 + threadIdx.x; i < n; i += gridDim.x * 256)
    dst[i] = f2b(src[i]);
}

// dproj (NB,NE,DIM,INNER) -> W2 (NB, DIM, NE*INNER) bf16
__global__ void cvt_dproj_k(const float* __restrict__ s, u16* __restrict__ d) {
  const int total = kNB * 4 * kDIM * 512;
  for (int i = blockIdx.x * blockDim.x + threadIdx.x; i < total; i += gridDim.x * blockDim.x) {
    int b = i >> 19;
    int r = i & 524287;
    int e = r >> 17;
    int r2 = r & 131071;
    int n = r2 >> 9;
    int j = r2 & 511;
    d[(size_t)b * 524288 + (size_t)n * 2048 + e * 512 + j] = f2b(s[i]);
  }
}

// x (DIM, L) f32 -> xT (L, DIM) bf16
__global__ __launch_bounds__(256) void transpose_x_k(const float* __restrict__ x, u16* __restrict__ xT) {
  __shared__ float tile[32][33];
  int l0 = blockIdx.x * 32, d0 = blockIdx.y * 32;
  int tx = threadIdx.x, ty = threadIdx.y;
  #pragma unroll
  for (int i = 0; i < 32; i += 8)
    tile[ty + i][tx] = x[(size_t)(d0 + ty + i) * kL + l0 + tx];
  __syncthreads();
  #pragma unroll
  for (int i = 0; i < 32; i += 8)
    xT[(size_t)(l0 + ty + i) * kDIM + d0 + tx] = f2b(tile[tx][ty + i]);
}

// ---------------- templated MFMA GEMM: C(MxN) = A(MxK) @ W(NxK)^T ----------------
// MODE 0: f32 store; 2: bf16 store; 3: silu->bf16 store; 4: f32 atomicAdd (split-K)
// LDS 16B-chunk XOR swizzle: element (row,col) lives at row*64 + ((col>>3)^(row&7))*8 + (col&7)
template <int BM, int BN, int TR, int TC, int WCN, int MODE>
__global__ __launch_bounds__(256) void gemm_t(
    const u16* __restrict__ A, int lda,
    const u16* __restrict__ W, int ldw,
    void* __restrict__ C, int ldc,
    int N, int K)
{
  constexpr int BNR = (BN + 63) & ~63;
  __shared__ u16 As[BM * 64];
  __shared__ u16 Bs[BNR * 64];
  const int tid = threadIdx.x;
  const int lane = tid & 63;
  const int wave = tid >> 6;
  const int bm = blockIdx.x * BM;
  const int bn = blockIdx.y * BN;
  const int wrow = (wave / WCN) * (TR * 16);
  const int wcol = (wave % WCN) * (TC * 16);
  const int kchunk = K / (int)gridDim.z;
  const int kbeg = blockIdx.z * kchunk;
  const int kend = kbeg + kchunk;

  f32x4 acc[TR][TC];
  #pragma unroll
  for (int r = 0; r < TR; ++r)
    #pragma unroll
    for (int c = 0; c < TC; ++c)
      acc[r][c] = f32x4{0.f, 0.f, 0.f, 0.f};

  for (int k0 = kbeg; k0 < kend; k0 += 64) {
    #pragma unroll
    for (int it = 0; it < BM * 64 / 2048; ++it) {
      int flat = (it * 256 + tid) * 8;
      int r = flat >> 6;
      int gc = ((((flat >> 3) & 7) ^ (r & 7)) << 3);
      async_cp16(A + (size_t)(bm + r) * lda + k0 + gc, &As[flat]);
    }
    #pragma unroll
    for (int it = 0; it < BNR * 64 / 2048; ++it) {
      int flat = (it * 256 + tid) * 8;
      int r = flat >> 6;
      int gc = ((((flat >> 3) & 7) ^ (r & 7)) << 3);
      int n = bn + r;
      if (n > N - 1) n = N - 1;
      async_cp16(W + (size_t)n * ldw + k0 + gc, &Bs[flat]);
    }
    __syncthreads();
    const int mrow = lane & 15;
    #pragma unroll
    for (int kk = 0; kk < 64; kk += 32) {
      const int kc = (kk >> 3) + (lane >> 4);  // 16B-chunk index 0..7
      bf16x8 a[TR], b[TC];
      #pragma unroll
      for (int rr = 0; rr < TR; ++rr) {
        int row = wrow + rr * 16 + mrow;
        a[rr] = *(const bf16x8*)&As[row * 64 + ((kc ^ (row & 7)) << 3)];
      }
      #pragma unroll
      for (int cc = 0; cc < TC; ++cc) {
        int row = wcol + cc * 16 + mrow;
        b[cc] = *(const bf16x8*)&Bs[row * 64 + ((kc ^ (row & 7)) << 3)];
      }
      #pragma unroll
      for (int rr = 0; rr < TR; ++rr)
        #pragma unroll
        for (int cc = 0; cc < TC; ++cc)
          acc[rr][cc] = __builtin_amdgcn_mfma_f32_16x16x32_bf16(a[rr], b[cc], acc[rr][cc], 0, 0, 0);
    }
    __syncthreads();
  }

  const int colb = bn + wcol + (lane & 15);
  const int rowb = bm + wrow + ((lane >> 4) << 2);
  #pragma unroll
  for (int rr = 0; rr < TR; ++rr)
    #pragma unroll
    for (int cc = 0; cc < TC; ++cc) {
      int col = colb + cc * 16;
      if (col >= N) continue;
      #pragma unroll
      for (int i = 0; i < 4; ++i) {
        size_t off = (size_t)(rowb + rr * 16 + i) * ldc + col;
        float v = acc[rr][cc][i];
        if constexpr (MODE == 0) ((float*)C)[off] = v;
        else if constexpr (MODE == 2) ((u16*)C)[off] = f2b(v);
        else if constexpr (MODE == 3) ((u16*)C)[off] = f2b(v * sigm(v));
        else atomicAdd(&((float*)C)[off], v);
      }
    }
}

// ---------------- block-wide sum over 256 threads (reusable) ----------------
__device__ __forceinline__ float block_sum256(float v) {
  #pragma unroll
  for (int o = 32; o > 0; o >>= 1) v += __shfl_down(v, o);
  __shared__ float red[4];
  __syncthreads();
  if ((threadIdx.x & 63) == 0) red[threadIdx.x >> 6] = v;
  __syncthreads();
  return red[0] + red[1] + red[2] + red[3];
}

// rmsnorm(h)*w -> bf16
__global__ __launch_bounds__(256) void rms_a_k(const float* __restrict__ h, const float* __restrict__ w,
                                               u16* __restrict__ hn) {
  const int l = blockIdx.x, t = threadIdx.x;
  const float v = h[(size_t)l * kDIM + t];
  const float ssum = block_sum256(v * v);
  const float r = rsqrtf(ssum * (1.f / 256.f) + kEPS);
  hn[(size_t)l * kDIM + t] = f2b(w[t] * v * r);
}

// h = h + rmsnorm_f(moe); emit hb2 = bf16(h) and hn = bf16(rmsnorm_a(h)) for next block
__global__ __launch_bounds__(256) void rms_f_fused_k(const float* __restrict__ moe,
                                                     const float* __restrict__ wf,
                                                     const float* __restrict__ wa,
                                                     float* __restrict__ h,
                                                     u16* __restrict__ hb2, u16* __restrict__ hn) {
  const int l = blockIdx.x, t = threadIdx.x;
  const float m = moe[(size_t)l * kDIM + t];
  const float r1 = rsqrtf(block_sum256(m * m) * (1.f / 256.f) + kEPS);
  const float hv = h[(size_t)l * kDIM + t] + wf[t] * m * r1;
  h[(size_t)l * kDIM + t] = hv;
  hb2[(size_t)l * kDIM + t] = f2b(hv);
  const float r2 = rsqrtf(block_sum256(hv * hv) * (1.f / 256.f) + kEPS);
  hn[(size_t)l * kDIM + t] = f2b(wa[t] * hv * r2);
}

// causal depthwise conv (4 taps) + bias + silu
__global__ __launch_bounds__(256) void conv_silu_k(const float* __restrict__ xz, const float* __restrict__ cw,
                                                   const float* __restrict__ cb, float* __restrict__ xc,
                                                   u16* __restrict__ xcb) {
  const int idx = blockIdx.x * 256 + threadIdx.x;  // L*DI
  const int l = idx >> 9, d = idx & 511;
  float acc = cb[d];
  #pragma unroll
  for (int j = 0; j < 4; ++j) {
    int ll = l - 3 + j;
    if (ll >= 0) acc += cw[d * 4 + j] * xz[(size_t)ll * 1024 + d];
  }
  const float s = acc * sigm(acc);
  xc[idx] = s;
  xcb[idx] = f2b(s);
}

__device__ __forceinline__ float softplus_f(float x) {
  return fmaxf(x, 0.f) + log1pf(__expf(-fabsf(x)));
}

// ---------------- 3-phase chunked selective scan, dt fused ----------------
__global__ __launch_bounds__(256) void scan_a_k(const float* __restrict__ xdbl, const float* __restrict__ xc,
                                                const float* __restrict__ A_log, const float* __restrict__ dtw,
                                                const float* __restrict__ dtb,
                                                float* __restrict__ aprod, float* __restrict__ bacc) {
  const int c = blockIdx.x;
  const int d = blockIdx.y * 256 + threadIdx.x;
  const int l0 = c * 64;
  __shared__ float Xs[64][32];  // [lr][0:16)=dr, [16:32)=B
  for (int i = threadIdx.x; i < 2048; i += 256) {
    int lr = i >> 5, j = i & 31;
    Xs[lr][j] = xdbl[(size_t)(l0 + lr) * 48 + j];
  }
  __syncthreads();
  float wd[16];
  #pragma unroll
  for (int r = 0; r < 16; ++r) wd[r] = dtw[d * 16 + r];
  const float bd = dtb[d];
  float Ad[16];
  #pragma unroll
  for (int n = 0; n < 16; ++n) Ad[n] = -__expf(A_log[d * 16 + n]);
  float s[16], ap[16];
  #pragma unroll
  for (int n = 0; n < 16; ++n) { s[n] = 0.f; ap[n] = 1.f; }
  for (int lr = 0; lr < 64; ++lr) {
    float dot = bd;
    #pragma unroll
    for (int r = 0; r < 16; ++r) dot = fmaf(Xs[lr][r], wd[r], dot);
    const float dl = softplus_f(dot);
    const float du = dl * xc[(size_t)(l0 + lr) * 512 + d];
    #pragma unroll
    for (int n = 0; n < 16; ++n) {
      const float a = __expf(dl * Ad[n]);
      s[n] = fmaf(a, s[n], du * Xs[lr][16 + n]);
      ap[n] *= a;
    }
  }
  const int o = (c * 512 + d) * 16;
  #pragma unroll
  for (int n = 0; n < 16; ++n) { aprod[o + n] = ap[n]; bacc[o + n] = s[n]; }
}

__global__ __launch_bounds__(256) void scan_b_k(const float* __restrict__ aprod, const float* __restrict__ bacc,
                                                float* __restrict__ sinit) {
  const int t = blockIdx.x * 256 + threadIdx.x;  // DI*NS = 8192
  float s = 0.f;
  #pragma unroll 4
  for (int c = 0; c < 128; ++c) {
    sinit[(size_t)c * 8192 + t] = s;
    s = fmaf(aprod[(size_t)c * 8192 + t], s, bacc[(size_t)c * 8192 + t]);
  }
}

__global__ __launch_bounds__(256) void scan_c_k(const float* __restrict__ xdbl, const float* __restrict__ xc,
                                                const float* __restrict__ xz, const float* __restrict__ A_log,
                                                const float* __restrict__ dtw, const float* __restrict__ dtb,
                                                const float* __restrict__ sinit,
                                                const float* __restrict__ Dp, u16* __restrict__ yv) {
  const int c = blockIdx.x;
  const int d = blockIdx.y * 256 + threadIdx.x;
  const int l0 = c * 64;
  __shared__ float Xs[64][48];  // dr | B | C
  for (int i = threadIdx.x; i < 3072; i += 256) {
    int lr = i / 48, j = i - lr * 48;
    Xs[lr][j] = xdbl[(size_t)(l0 + lr) * 48 + j];
  }
  __syncthreads();
  float wd[16];
  #pragma unroll
  for (int r = 0; r < 16; ++r) wd[r] = dtw[d * 16 + r];
  const float bd = dtb[d];
  float Ad[16];
  #pragma unroll
  for (int n = 0; n < 16; ++n) Ad[n] = -__expf(A_log[d * 16 + n]);
  float s[16];
  const int o = (c * 512 + d) * 16;
  #pragma unroll
  for (int n = 0; n < 16; ++n) s[n] = sinit[o + n];
  const float Dd = Dp[d];
  for (int lr = 0; lr < 64; ++lr) {
    const int l = l0 + lr;
    float dot = bd;
    #pragma unroll
    for (int r = 0; r < 16; ++r) dot = fmaf(Xs[lr][r], wd[r], dot);
    const float dl = softplus_f(dot);
    const float xv = xc[(size_t)l * 512 + d];
    const float du = dl * xv;
    float y = 0.f;
    #pragma unroll
    for (int n = 0; n < 16; ++n) {
      const float a = __expf(dl * Ad[n]);
      s[n] = fmaf(a, s[n], du * Xs[lr][16 + n]);
      y = fmaf(s[n], Xs[lr][32 + n], y);
    }
    const float z = xz[(size_t)l * 1024 + 512 + d];
    y = (y + xv * Dd) * (z * sigm(z));
    yv[(size_t)l * 512 + d] = f2b(y);
  }
}

// router: top-2 softmax weights; also bf16 copy of h
__global__ __launch_bounds__(256) void router_k(const float* __restrict__ h, const float* __restrict__ gw,
                                                float* __restrict__ we, u16* __restrict__ hb) {
  const int l = blockIdx.x * 4 + (threadIdx.x >> 6);
  const int lane = threadIdx.x & 63;
  const float4 v = reinterpret_cast<const float4*>(h + (size_t)l * 256)[lane];
  ushort4 hv = make_ushort4(f2b(v.x), f2b(v.y), f2b(v.z), f2b(v.w));
  reinterpret_cast<ushort4*>(hb + (size_t)l * 256)[lane] = hv;
  float p[4];
  #pragma unroll
  for (int e = 0; e < 4; ++e) {
    const float4 g = reinterpret_cast<const float4*>(gw + (size_t)e * 256)[lane];
    p[e] = v.x * g.x + v.y * g.y + v.z * g.z + v.w * g.w;
  }
  #pragma unroll
  for (int o = 32; o > 0; o >>= 1) {
    p[0] += __shfl_down(p[0], o);
    p[1] += __shfl_down(p[1], o);
    p[2] += __shfl_down(p[2], o);
    p[3] += __shfl_down(p[3], o);
  }
  if (lane == 0) {
    int i0 = 0;
    #pragma unroll
    for (int e = 1; e < 4; ++e) if (p[e] > p[i0]) i0 = e;
    int i1 = -1;
    #pragma unroll
    for (int e = 0; e < 4; ++e) {
      if (e == i0) continue;
      if (i1 < 0 || p[e] > p[i1]) i1 = e;
    }
    const float t = __expf(p[i1] - p[i0]);
    const float w0 = 1.f / (1.f + t);
    const float w1 = t / (1.f + t);
    float o[4] = {0.f, 0.f, 0.f, 0.f};
    o[i0] = w0; o[i1] = w1;
    reinterpret_cast<float4*>(we)[l] = make_float4(o[0], o[1], o[2], o[3]);
  }
}

// ts = silu(g)*u*we  (merged gu layout: g at [l,0:2048), u at [l,2048:4096))
__global__ __launch_bounds__(256) void mix_glu_k(const u16* __restrict__ gu,
                                                 const float* __restrict__ we, u16* __restrict__ ts) {
  const int i4 = blockIdx.x * 256 + threadIdx.x;  // L*2048/4
  const int base = i4 * 4;
  const int l = base >> 11;
  const int m = base & 2047;
  const float w = we[l * 4 + (m >> 9)];
  const ushort4 gv = *(const ushort4*)&gu[(size_t)l * 4096 + m];
  const ushort4 uv = *(const ushort4*)&gu[(size_t)l * 4096 + 2048 + m];
  float g0 = b2f(gv.x), g1 = b2f(gv.y), g2 = b2f(gv.z), g3 = b2f(gv.w);
  ushort4 o;
  o.x = f2b(g0 * sigm(g0) * b2f(uv.x) * w);
  o.y = f2b(g1 * sigm(g1) * b2f(uv.y) * w);
  o.z = f2b(g2 * sigm(g2) * b2f(uv.z) * w);
  o.w = f2b(g3 * sigm(g3) * b2f(uv.w) * w);
  *(ushort4*)&ts[(size_t)l * 2048 + m] = o;
}

// out[o,l] = sigmoid(g2[l,o])
__global__ __launch_bounds__(256) void sig_t_k(const float* __restrict__ g2, float* __restrict__ out) {
  __shared__ float tl[32][33];
  const int l0 = blockIdx.x * 32;
  const int t = threadIdx.x;
  const int r = t >> 5, c = t & 31;
  #pragma unroll
  for (int j = 0; j < 4; ++j) {
    int li = r * 4 + j;
    tl[li][c] = g2[(size_t)(l0 + li) * 32 + c];
  }
  __syncthreads();
  #pragma unroll
  for (int j = 0; j < 4; ++j) {
    int oo = r * 4 + j;
    out[(size_t)oo * kL + l0 + c] = sigm(tl[c][oo]);
  }
}

extern "C" void kernel_launch(void* const* d_in, const int* in_sizes, int n_in,
                              void* d_out, int out_size, void* d_ws, size_t ws_size,
                              hipStream_t stream) {
  const float* x        = (const float*)d_in[0];
  const float* lin_w    = (const float*)d_in[1];
  const float* in_proj  = (const float*)d_in[2];
  const float* conv_w   = (const float*)d_in[3];
  const float* conv_b   = (const float*)d_in[4];
  const float* x_proj   = (const float*)d_in[5];
  const float* dt_w     = (const float*)d_in[6];
  const float* dt_b     = (const float*)d_in[7];
  const float* A_log    = (const float*)d_in[8];
  const float* D_param  = (const float*)d_in[9];
  const float* out_proj = (const float*)d_in[10];
  const float* gate_w   = (const float*)d_in[11];
  const float* gproj    = (const float*)d_in[12];
  const float* uproj    = (const float*)d_in[13];
  const float* dproj    = (const float*)d_in[14];
  const float* rms_a_w  = (const float*)d_in[15];
  const float* rms_f_w  = (const float*)d_in[16];
  const float* head_w1  = (const float*)d_in[17];
  const float* head_w2  = (const float*)d_in[18];

  char* p = (char*)d_ws;
  auto alloc = [&](size_t bytes) -> char* {
    char* r = p;
    p += (bytes + 255) & ~(size_t)255;
    return r;
  };

  // bf16 weight pool
  u16* lin_b  = (u16*)alloc(65536 * 2);
  u16* ipw_b  = (u16*)alloc((size_t)2097152 * 2);
  u16* xpw_b  = (u16*)alloc((size_t)196608 * 2);
  u16* opw_b  = (u16*)alloc((size_t)1048576 * 2);
  u16* gupw_b = (u16*)alloc((size_t)8388608 * 2);  // per block: [g 2048 rows; u 2048 rows] x 256
  u16* dpw_b  = (u16*)alloc((size_t)4194304 * 2);
  u16* hw1_b  = (u16*)alloc(65536 * 2);
  u16* hw2_b  = (u16*)alloc(8192 * 2);

  // activations
  u16* xT    = (u16*)alloc((size_t)kL * kDIM * 2);
  float* h   = (float*)alloc((size_t)kL * kDIM * 4);
  u16* hn    = (u16*)alloc((size_t)kL * kDIM * 2);
  u16* hb    = (u16*)alloc((size_t)kL * kDIM * 2);
  u16* hb2   = (u16*)alloc((size_t)kL * kDIM * 2);
  float* we  = (float*)alloc((size_t)kL * 4 * 4);
  float* xdbl = (float*)alloc((size_t)kL * 48 * 4);
  float* g2o  = (float*)alloc((size_t)kL * 32 * 4);
  u16* fb    = (u16*)alloc((size_t)kL * kDIM * 2);
  u16* h2b   = (u16*)alloc((size_t)kL * kDIM * 2);
  char* un   = alloc((size_t)67108864);  // xz f32 (32MB, first half) | gu bf16 (64MB)
  float* xz  = (float*)un;
  u16* gu    = (u16*)un;
  u16* ts    = (u16*)alloc((size_t)kL * 2048 * 2);
  float* xc  = (float*)alloc((size_t)kL * kDI * 4);
  u16* xcb   = (u16*)alloc((size_t)kL * kDI * 2);
  u16* yv    = (u16*)alloc((size_t)kL * kDI * 2);
  float* aprod = (float*)alloc((size_t)128 * 8192 * 4);
  float* bacc  = (float*)alloc((size_t)128 * 8192 * 4);
  float* sinit = (float*)alloc((size_t)128 * 8192 * 4);
  float* moe   = (float*)alloc((size_t)kL * kDIM * 4);

  if ((size_t)(p - (char*)d_ws) > ws_size) return;  // fail loudly

  // ---- weight conversion (2 launches) ----
  CvtDescs dd;
  int seg = 0;
  auto add = [&](const float* s, u16* d, int n) { dd.s[seg] = s; dd.d[seg] = d; dd.n[seg] = n; ++seg; };
  add(lin_w, lin_b, 65536);
  add(in_proj, ipw_b, 2097152);
  add(x_proj, xpw_b, 196608);
  add(out_proj, opw_b, 1048576);
  add(head_w1, hw1_b, 65536);
  add(head_w2, hw2_b, 8192);
  for (int i = 0; i < kNB; ++i) {
    add(gproj + (size_t)i * 524288, gupw_b + (size_t)i * 1048576, 524288);
    add(uproj + (size_t)i * 524288, gupw_b + (size_t)i * 1048576 + 524288, 524288);
  }
  cvt_multi_k<<<dim3(64, 22), 256, 0, stream>>>(dd);
  cvt_dproj_k<<<2048, 256, 0, stream>>>(dproj, dpw_b);
  transpose_x_k<<<dim3(kL / 32, kDIM / 32), dim3(32, 8), 0, stream>>>(x, xT);

  // h = xT @ lin_w^T   (M=8192, N=256, K=256)
  gemm_t<64, 128, 2, 4, 2, 0><<<dim3(128, 2, 1), 256, 0, stream>>>(xT, 256, lin_b, 256, h, 256, 256, 256);
  rms_a_k<<<kL, 256, 0, stream>>>(h, rms_a_w, hn);

  for (int i = 0; i < kNB; ++i) {
    // in_proj: N=1024, K=256
    gemm_t<128, 128, 4, 4, 2, 0><<<dim3(64, 8, 1), 256, 0, stream>>>(
        hn, 256, ipw_b + (size_t)i * 262144, 256, xz, 1024, 1024, 256);
    conv_silu_k<<<kL * kDI / 256, 256, 0, stream>>>(xz, conv_w + (size_t)i * 2048,
                                                    conv_b + (size_t)i * 512, xc, xcb);
    // xdbl: N=48, K=512, split-K=8 atomic
    hipMemsetAsync(xdbl, 0, (size_t)kL * 48 * 4, stream);
    gemm_t<128, 48, 2, 3, 1, 4><<<dim3(64, 1, 8), 256, 0, stream>>>(
        xcb, 512, xpw_b + (size_t)i * 24576, 512, xdbl, 48, 48, 512);
    scan_a_k<<<dim3(128, 2), 256, 0, stream>>>(xdbl, xc, A_log + (size_t)i * 8192,
                                               dt_w + (size_t)i * 8192, dt_b + (size_t)i * 512,
                                               aprod, bacc);
    scan_b_k<<<32, 256, 0, stream>>>(aprod, bacc, sinit);
    scan_c_k<<<dim3(128, 2), 256, 0, stream>>>(xdbl, xc, xz, A_log + (size_t)i * 8192,
                                               dt_w + (size_t)i * 8192, dt_b + (size_t)i * 512,
                                               sinit, D_param + (size_t)i * 512, yv);
    // out_proj: h += yv @ opw^T, N=256, K=512, split-K=4 atomic
    gemm_t<128, 128, 4, 4, 2, 4><<<dim3(64, 2, 4), 256, 0, stream>>>(
        yv, 512, opw_b + (size_t)i * 131072, 512, h, 256, 256, 512);
    router_k<<<kL / 4, 256, 0, stream>>>(h, gate_w + (size_t)i * 1024, we, hb);
    // merged g+u: N=4096, K=256
    gemm_t<128, 128, 4, 4, 2, 2><<<dim3(64, 32, 1), 256, 0, stream>>>(
        hb, 256, gupw_b + (size_t)i * 1048576, 256, gu, 4096, 4096, 256);
    mix_glu_k<<<kL * 2048 / 1024, 256, 0, stream>>>(gu, we, ts);
    // dproj: N=256, K=2048, split-K=4 atomic
    hipMemsetAsync(moe, 0, (size_t)kL * kDIM * 4, stream);
    gemm_t<128, 128, 4, 4, 2, 4><<<dim3(64, 2, 4), 256, 0, stream>>>(
        ts, 2048, dpw_b + (size_t)i * 524288, 2048, moe, 256, 256, 2048);
    rms_f_fused_k<<<kL, 256, 0, stream>>>(moe, rms_f_w, rms_a_w, h, hb2, hn);
  }

  // head
  gemm_t<64, 128, 2, 4, 2, 2><<<dim3(128, 2, 1), 256, 0, stream>>>(hb2, 256, lin_b, 256, h2b, 256, 256, 256);
  gemm_t<64, 128, 2, 4, 2, 3><<<dim3(128, 2, 1), 256, 0, stream>>>(h2b, 256, hw1_b, 256, fb, 256, 256, 256);
  gemm_t<64, 128, 2, 4, 2, 0><<<dim3(128, 1, 1), 256, 0, stream>>>(fb, 256, hw2_b, 256, g2o, 32, 32, 256);
  sig_t_k<<<kL / 32, 256, 0, stream>>>(g2o, (float*)d_out);
}

// Round 3
// 2270.142 us; speedup vs baseline: 1.1729x; 1.1729x over previous
//
#include <hip/hip_runtime.h>

typedef unsigned short u16;
typedef unsigned int u32;
using bf16x8 = __attribute__((ext_vector_type(8))) short;
using f32x4 = __attribute__((ext_vector_type(4))) float;

constexpr int kL = 8192;
constexpr int kDIM = 256;
constexpr int kDI = 512;
constexpr int kNB = 8;
constexpr float kEPS = 1e-3f;

__device__ __forceinline__ u16 f2b(float f) {
  u32 x = __builtin_bit_cast(u32, f);
  x += 0x7fffu + ((x >> 16) & 1u);
  return (u16)(x >> 16);
}
__device__ __forceinline__ float b2f(u16 u) {
  return __builtin_bit_cast(float, (u32)u << 16);
}
__device__ __forceinline__ float sigm(float x) { return 1.f / (1.f + __expf(-x)); }
__device__ __forceinline__ float softplus_fast(float x) {
  return fmaxf(x, 0.f) + __logf(1.f + __expf(-fabsf(x)));
}

__device__ __forceinline__ void async_cp16(const void* g, void* l) {
  __builtin_amdgcn_global_load_lds((const __attribute__((address_space(1))) u32*)g,
                                   (__attribute__((address_space(3))) u32*)l, 16, 0, 0);
}

// ---------------- weight conversion ----------------
struct CvtDescs {
  const float* s[22];
  u16* d[22];
  int n[22];
};
__global__ __launch_bounds__(256) void cvt_multi_k(CvtDescs dd) {
  const int seg = blockIdx.y;
  const float* src = dd.s[seg];
  u16* dst = dd.d[seg];
  const int n = dd.n[seg];
  for (int i = blockIdx.x * 256 + threadIdx.x; i < n; i += gridDim.x * 256)
    dst[i] = f2b(src[i]);
}

__global__ void cvt_dproj_k(const float* __restrict__ s, u16* __restrict__ d) {
  const int total = kNB * 4 * kDIM * 512;
  for (int i = blockIdx.x * blockDim.x + threadIdx.x; i < total; i += gridDim.x * blockDim.x) {
    int b = i >> 19;
    int r = i & 524287;
    int e = r >> 17;
    int r2 = r & 131071;
    int n = r2 >> 9;
    int j = r2 & 511;
    d[(size_t)b * 524288 + (size_t)n * 2048 + e * 512 + j] = f2b(s[i]);
  }
}

__global__ __launch_bounds__(256) void transpose_x_k(const float* __restrict__ x, u16* __restrict__ xT) {
  __shared__ float tile[32][33];
  int l0 = blockIdx.x * 32, d0 = blockIdx.y * 32;
  int tx = threadIdx.x, ty = threadIdx.y;
  #pragma unroll
  for (int i = 0; i < 32; i += 8)
    tile[ty + i][tx] = x[(size_t)(d0 + ty + i) * kL + l0 + tx];
  __syncthreads();
  #pragma unroll
  for (int i = 0; i < 32; i += 8)
    xT[(size_t)(l0 + ty + i) * kDIM + d0 + tx] = f2b(tile[tx][ty + i]);
}

// ---------------- templated MFMA GEMM: C(MxN) = A(MxK) @ W(NxK)^T ----------------
// MODE 0: f32 store; 2: bf16 store; 3: silu->bf16 store; 4: f32 atomicAdd (split-K)
template <int BM, int BN, int TR, int TC, int WCN, int MODE>
__global__ __launch_bounds__(256) void gemm_t(
    const u16* __restrict__ A, int lda,
    const u16* __restrict__ W, int ldw,
    void* __restrict__ C, int ldc,
    int N, int K)
{
  constexpr int BNR = (BN + 63) & ~63;
  __shared__ u16 As[BM * 64];
  __shared__ u16 Bs[BNR * 64];
  const int tid = threadIdx.x;
  const int lane = tid & 63;
  const int wave = tid >> 6;
  const int bm = blockIdx.x * BM;
  const int bn = blockIdx.y * BN;
  const int wrow = (wave / WCN) * (TR * 16);
  const int wcol = (wave % WCN) * (TC * 16);
  const int kchunk = K / (int)gridDim.z;
  const int kbeg = blockIdx.z * kchunk;
  const int kend = kbeg + kchunk;

  f32x4 acc[TR][TC];
  #pragma unroll
  for (int r = 0; r < TR; ++r)
    #pragma unroll
    for (int c = 0; c < TC; ++c)
      acc[r][c] = f32x4{0.f, 0.f, 0.f, 0.f};

  for (int k0 = kbeg; k0 < kend; k0 += 64) {
    #pragma unroll
    for (int it = 0; it < BM * 64 / 2048; ++it) {
      int flat = (it * 256 + tid) * 8;
      int r = flat >> 6;
      int gc = ((((flat >> 3) & 7) ^ (r & 7)) << 3);
      async_cp16(A + (size_t)(bm + r) * lda + k0 + gc, &As[flat]);
    }
    #pragma unroll
    for (int it = 0; it < BNR * 64 / 2048; ++it) {
      int flat = (it * 256 + tid) * 8;
      int r = flat >> 6;
      int gc = ((((flat >> 3) & 7) ^ (r & 7)) << 3);
      int n = bn + r;
      if (n > N - 1) n = N - 1;
      async_cp16(W + (size_t)n * ldw + k0 + gc, &Bs[flat]);
    }
    __syncthreads();
    const int mrow = lane & 15;
    #pragma unroll
    for (int kk = 0; kk < 64; kk += 32) {
      const int kc = (kk >> 3) + (lane >> 4);
      bf16x8 a[TR], b[TC];
      #pragma unroll
      for (int rr = 0; rr < TR; ++rr) {
        int row = wrow + rr * 16 + mrow;
        a[rr] = *(const bf16x8*)&As[row * 64 + ((kc ^ (row & 7)) << 3)];
      }
      #pragma unroll
      for (int cc = 0; cc < TC; ++cc) {
        int row = wcol + cc * 16 + mrow;
        b[cc] = *(const bf16x8*)&Bs[row * 64 + ((kc ^ (row & 7)) << 3)];
      }
      #pragma unroll
      for (int rr = 0; rr < TR; ++rr)
        #pragma unroll
        for (int cc = 0; cc < TC; ++cc)
          acc[rr][cc] = __builtin_amdgcn_mfma_f32_16x16x32_bf16(a[rr], b[cc], acc[rr][cc], 0, 0, 0);
    }
    __syncthreads();
  }

  const int colb = bn + wcol + (lane & 15);
  const int rowb = bm + wrow + ((lane >> 4) << 2);
  #pragma unroll
  for (int rr = 0; rr < TR; ++rr)
    #pragma unroll
    for (int cc = 0; cc < TC; ++cc) {
      int col = colb + cc * 16;
      if (col >= N) continue;
      #pragma unroll
      for (int i = 0; i < 4; ++i) {
        size_t off = (size_t)(rowb + rr * 16 + i) * ldc + col;
        float v = acc[rr][cc][i];
        if constexpr (MODE == 0) ((float*)C)[off] = v;
        else if constexpr (MODE == 2) ((u16*)C)[off] = f2b(v);
        else if constexpr (MODE == 3) ((u16*)C)[off] = f2b(v * sigm(v));
        else atomicAdd(&((float*)C)[off], v);
      }
    }
}

// ---------------- block-wide sum over 256 threads ----------------
__device__ __forceinline__ float block_sum256(float v) {
  #pragma unroll
  for (int o = 32; o > 0; o >>= 1) v += __shfl_down(v, o);
  __shared__ float red[4];
  __syncthreads();
  if ((threadIdx.x & 63) == 0) red[threadIdx.x >> 6] = v;
  __syncthreads();
  return red[0] + red[1] + red[2] + red[3];
}

__global__ __launch_bounds__(256) void rms_a_k(const float* __restrict__ h, const float* __restrict__ w,
                                               u16* __restrict__ hn) {
  const int l = blockIdx.x, t = threadIdx.x;
  const float v = h[(size_t)l * kDIM + t];
  const float ssum = block_sum256(v * v);
  const float r = rsqrtf(ssum * (1.f / 256.f) + kEPS);
  hn[(size_t)l * kDIM + t] = f2b(w[t] * v * r);
}

__global__ __launch_bounds__(256) void rms_f_fused_k(const float* __restrict__ moe,
                                                     const float* __restrict__ wf,
                                                     const float* __restrict__ wa,
                                                     float* __restrict__ h,
                                                     u16* __restrict__ hb2, u16* __restrict__ hn) {
  const int l = blockIdx.x, t = threadIdx.x;
  const float m = moe[(size_t)l * kDIM + t];
  const float r1 = rsqrtf(block_sum256(m * m) * (1.f / 256.f) + kEPS);
  const float hv = h[(size_t)l * kDIM + t] + wf[t] * m * r1;
  h[(size_t)l * kDIM + t] = hv;
  hb2[(size_t)l * kDIM + t] = f2b(hv);
  const float r2 = rsqrtf(block_sum256(hv * hv) * (1.f / 256.f) + kEPS);
  hn[(size_t)l * kDIM + t] = f2b(wa[t] * hv * r2);
}

// causal depthwise conv (4 taps) + bias + silu -> xcb bf16; z*silu(z) -> zsb bf16
__global__ __launch_bounds__(256) void conv_silu_k(const u16* __restrict__ xz, const float* __restrict__ cw,
                                                   const float* __restrict__ cb,
                                                   u16* __restrict__ xcb, u16* __restrict__ zsb) {
  const int idx = blockIdx.x * 256 + threadIdx.x;  // L*DI
  const int l = idx >> 9, d = idx & 511;
  float acc = cb[d];
  #pragma unroll
  for (int j = 0; j < 4; ++j) {
    int ll = l - 3 + j;
    if (ll >= 0) acc += cw[d * 4 + j] * b2f(xz[(size_t)ll * 1024 + d]);
  }
  const float s = acc * sigm(acc);
  xcb[idx] = f2b(s);
  const float z = b2f(xz[(size_t)l * 1024 + 512 + d]);
  zsb[idx] = f2b(z * sigm(z));
}

// ---------------- chunked selective scan; lane-pair state split ----------------
// thread t: dloc = t>>1, half = t&1, d = blockIdx.y*128 + dloc; 8 states each.
__global__ __launch_bounds__(256) void scan_a_k(const float* __restrict__ xdbl, const u16* __restrict__ xcb,
                                                const float* __restrict__ A_log, const float* __restrict__ dtw,
                                                const float* __restrict__ dtb,
                                                float* __restrict__ delta,
                                                float* __restrict__ aprod, float* __restrict__ bacc) {
  const int c = blockIdx.x;
  const int t = threadIdx.x;
  const int half = t & 1;
  const int d = blockIdx.y * 128 + (t >> 1);
  const int l0 = c * 64;
  __shared__ float Xs[64][32];  // [lr][0:16)=dr, [16:32)=B
  for (int i = t; i < 2048; i += 256)
    Xs[i >> 5][i & 31] = xdbl[(size_t)(l0 + (i >> 5)) * 48 + (i & 31)];
  __syncthreads();
  float wd[8], Ad[8];
  #pragma unroll
  for (int j = 0; j < 8; ++j) wd[j] = dtw[d * 16 + half * 8 + j];
  const float bd = dtb[d];
  #pragma unroll
  for (int n = 0; n < 8; ++n) Ad[n] = -__expf(A_log[d * 16 + half * 8 + n]);
  float s[8], ap[8];
  #pragma unroll
  for (int n = 0; n < 8; ++n) { s[n] = 0.f; ap[n] = 1.f; }
  #pragma unroll 4
  for (int lr = 0; lr < 64; ++lr) {
    const float4 dr0 = *(const float4*)&Xs[lr][half * 8];
    const float4 dr1 = *(const float4*)&Xs[lr][half * 8 + 4];
    float p0 = dr0.x * wd[0] + dr0.y * wd[1] + dr0.z * wd[2] + dr0.w * wd[3];
    float p1 = dr1.x * wd[4] + dr1.y * wd[5] + dr1.z * wd[6] + dr1.w * wd[7];
    float dot = p0 + p1;
    dot += __shfl_xor(dot, 1);
    const float dl = softplus_fast(dot + bd);
    const int l = l0 + lr;
    if (!half) delta[(size_t)l * 512 + d] = dl;
    const float du = dl * b2f(xcb[(size_t)l * 512 + d]);
    const float4 B0 = *(const float4*)&Xs[lr][16 + half * 8];
    const float4 B1 = *(const float4*)&Xs[lr][16 + half * 8 + 4];
    const float Bv[8] = {B0.x, B0.y, B0.z, B0.w, B1.x, B1.y, B1.z, B1.w};
    #pragma unroll
    for (int n = 0; n < 8; ++n) {
      const float a = __expf(dl * Ad[n]);
      s[n] = fmaf(a, s[n], du * Bv[n]);
      ap[n] *= a;
    }
  }
  const int base = c * 8192 + d * 16 + half * 8;
  #pragma unroll
  for (int n = 0; n < 8; ++n) { aprod[base + n] = ap[n]; bacc[base + n] = s[n]; }
}

// chunk combine, 3 levels: 128 chunks = 16 groups x 8
__global__ __launch_bounds__(256) void scan_b1_k(const float* __restrict__ aprod, const float* __restrict__ bacc,
                                                 float* __restrict__ gp, float* __restrict__ gb) {
  const int idx = blockIdx.x * 256 + threadIdx.x;  // 8192*16
  const int st = idx & 8191, g = idx >> 13;
  float P = 1.f, S = 0.f;
  #pragma unroll
  for (int k = 0; k < 8; ++k) {
    const int c = g * 8 + k;
    const float a = aprod[(size_t)c * 8192 + st];
    S = fmaf(a, S, bacc[(size_t)c * 8192 + st]);
    P *= a;
  }
  gp[(size_t)g * 8192 + st] = P;
  gb[(size_t)g * 8192 + st] = S;
}

__global__ __launch_bounds__(256) void scan_b2_k(const float* __restrict__ gp, const float* __restrict__ gb,
                                                 float* __restrict__ ginit) {
  const int st = blockIdx.x * 256 + threadIdx.x;  // 8192
  float cur = 0.f;
  #pragma unroll
  for (int g = 0; g < 16; ++g) {
    ginit[(size_t)g * 8192 + st] = cur;
    cur = fmaf(gp[(size_t)g * 8192 + st], cur, gb[(size_t)g * 8192 + st]);
  }
}

__global__ __launch_bounds__(256) void scan_b3_k(const float* __restrict__ aprod, const float* __restrict__ bacc,
                                                 const float* __restrict__ ginit, float* __restrict__ sinit) {
  const int idx = blockIdx.x * 256 + threadIdx.x;  // 8192*16
  const int st = idx & 8191, g = idx >> 13;
  float cur = ginit[(size_t)g * 8192 + st];
  #pragma unroll
  for (int k = 0; k < 8; ++k) {
    const int c = g * 8 + k;
    sinit[(size_t)c * 8192 + st] = cur;
    cur = fmaf(aprod[(size_t)c * 8192 + st], cur, bacc[(size_t)c * 8192 + st]);
  }
}

__global__ __launch_bounds__(256) void scan_c_k(const float* __restrict__ xdbl, const u16* __restrict__ xcb,
                                                const u16* __restrict__ zsb, const float* __restrict__ A_log,
                                                const float* __restrict__ delta,
                                                const float* __restrict__ sinit,
                                                const float* __restrict__ Dp, u16* __restrict__ yv) {
  const int c = blockIdx.x;
  const int t = threadIdx.x;
  const int half = t & 1;
  const int d = blockIdx.y * 128 + (t >> 1);
  const int l0 = c * 64;
  __shared__ float Xs[64][32];  // [lr][0:16)=B, [16:32)=C
  for (int i = t; i < 2048; i += 256)
    Xs[i >> 5][i & 31] = xdbl[(size_t)(l0 + (i >> 5)) * 48 + 16 + (i & 31)];
  __syncthreads();
  float Ad[8];
  #pragma unroll
  for (int n = 0; n < 8; ++n) Ad[n] = -__expf(A_log[d * 16 + half * 8 + n]);
  float s[8];
  const int base = c * 8192 + d * 16 + half * 8;
  #pragma unroll
  for (int n = 0; n < 8; ++n) s[n] = sinit[base + n];
  const float Dd = Dp[d];
  #pragma unroll 4
  for (int lr = 0; lr < 64; ++lr) {
    const int l = l0 + lr;
    const float dl = delta[(size_t)l * 512 + d];
    const float xv = b2f(xcb[(size_t)l * 512 + d]);
    const float zs = b2f(zsb[(size_t)l * 512 + d]);
    const float du = dl * xv;
    const float4 B0 = *(const float4*)&Xs[lr][half * 8];
    const float4 B1 = *(const float4*)&Xs[lr][half * 8 + 4];
    const float4 C0 = *(const float4*)&Xs[lr][16 + half * 8];
    const float4 C1 = *(const float4*)&Xs[lr][16 + half * 8 + 4];
    const float Bv[8] = {B0.x, B0.y, B0.z, B0.w, B1.x, B1.y, B1.z, B1.w};
    const float Cv[8] = {C0.x, C0.y, C0.z, C0.w, C1.x, C1.y, C1.z, C1.w};
    float y = 0.f;
    #pragma unroll
    for (int n = 0; n < 8; ++n) {
      const float a = __expf(dl * Ad[n]);
      s[n] = fmaf(a, s[n], du * Bv[n]);
      y = fmaf(s[n], Cv[n], y);
    }
    y += __shfl_xor(y, 1);
    if (!half) yv[(size_t)l * 512 + d] = f2b((y + xv * Dd) * zs);
  }
}

// router: top-2 softmax weights; also bf16 copy of h
__global__ __launch_bounds__(256) void router_k(const float* __restrict__ h, const float* __restrict__ gw,
                                                float* __restrict__ we, u16* __restrict__ hb) {
  const int l = blockIdx.x * 4 + (threadIdx.x >> 6);
  const int lane = threadIdx.x & 63;
  const float4 v = reinterpret_cast<const float4*>(h + (size_t)l * 256)[lane];
  ushort4 hv = make_ushort4(f2b(v.x), f2b(v.y), f2b(v.z), f2b(v.w));
  reinterpret_cast<ushort4*>(hb + (size_t)l * 256)[lane] = hv;
  float p[4];
  #pragma unroll
  for (int e = 0; e < 4; ++e) {
    const float4 g = reinterpret_cast<const float4*>(gw + (size_t)e * 256)[lane];
    p[e] = v.x * g.x + v.y * g.y + v.z * g.z + v.w * g.w;
  }
  #pragma unroll
  for (int o = 32; o > 0; o >>= 1) {
    p[0] += __shfl_down(p[0], o);
    p[1] += __shfl_down(p[1], o);
    p[2] += __shfl_down(p[2], o);
    p[3] += __shfl_down(p[3], o);
  }
  if (lane == 0) {
    int i0 = 0;
    #pragma unroll
    for (int e = 1; e < 4; ++e) if (p[e] > p[i0]) i0 = e;
    int i1 = -1;
    #pragma unroll
    for (int e = 0; e < 4; ++e) {
      if (e == i0) continue;
      if (i1 < 0 || p[e] > p[i1]) i1 = e;
    }
    const float t = __expf(p[i1] - p[i0]);
    const float w0 = 1.f / (1.f + t);
    const float w1 = t / (1.f + t);
    float o[4] = {0.f, 0.f, 0.f, 0.f};
    o[i0] = w0; o[i1] = w1;
    reinterpret_cast<float4*>(we)[l] = make_float4(o[0], o[1], o[2], o[3]);
  }
}

// ts = silu(g)*u*we  (merged gu layout)
__global__ __launch_bounds__(256) void mix_glu_k(const u16* __restrict__ gu,
                                                 const float* __restrict__ we, u16* __restrict__ ts) {
  const int i4 = blockIdx.x * 256 + threadIdx.x;  // L*2048/4
  const int base = i4 * 4;
  const int l = base >> 11;
  const int m = base & 2047;
  const float w = we[l * 4 + (m >> 9)];
  const ushort4 gv = *(const ushort4*)&gu[(size_t)l * 4096 + m];
  const ushort4 uv = *(const ushort4*)&gu[(size_t)l * 4096 + 2048 + m];
  float g0 = b2f(gv.x), g1 = b2f(gv.y), g2 = b2f(gv.z), g3 = b2f(gv.w);
  ushort4 o;
  o.x = f2b(g0 * sigm(g0) * b2f(uv.x) * w);
  o.y = f2b(g1 * sigm(g1) * b2f(uv.y) * w);
  o.z = f2b(g2 * sigm(g2) * b2f(uv.z) * w);
  o.w = f2b(g3 * sigm(g3) * b2f(uv.w) * w);
  *(ushort4*)&ts[(size_t)l * 2048 + m] = o;
}

__global__ __launch_bounds__(256) void sig_t_k(const float* __restrict__ g2, float* __restrict__ out) {
  __shared__ float tl[32][33];
  const int l0 = blockIdx.x * 32;
  const int t = threadIdx.x;
  const int r = t >> 5, c = t & 31;
  #pragma unroll
  for (int j = 0; j < 4; ++j) {
    int li = r * 4 + j;
    tl[li][c] = g2[(size_t)(l0 + li) * 32 + c];
  }
  __syncthreads();
  #pragma unroll
  for (int j = 0; j < 4; ++j) {
    int oo = r * 4 + j;
    out[(size_t)oo * kL + l0 + c] = sigm(tl[c][oo]);
  }
}

extern "C" void kernel_launch(void* const* d_in, const int* in_sizes, int n_in,
                              void* d_out, int out_size, void* d_ws, size_t ws_size,
                              hipStream_t stream) {
  const float* x        = (const float*)d_in[0];
  const float* lin_w    = (const float*)d_in[1];
  const float* in_proj  = (const float*)d_in[2];
  const float* conv_w   = (const float*)d_in[3];
  const float* conv_b   = (const float*)d_in[4];
  const float* x_proj   = (const float*)d_in[5];
  const float* dt_w     = (const float*)d_in[6];
  const float* dt_b     = (const float*)d_in[7];
  const float* A_log    = (const float*)d_in[8];
  const float* D_param  = (const float*)d_in[9];
  const float* out_proj = (const float*)d_in[10];
  const float* gate_w   = (const float*)d_in[11];
  const float* gproj    = (const float*)d_in[12];
  const float* uproj    = (const float*)d_in[13];
  const float* dproj    = (const float*)d_in[14];
  const float* rms_a_w  = (const float*)d_in[15];
  const float* rms_f_w  = (const float*)d_in[16];
  const float* head_w1  = (const float*)d_in[17];
  const float* head_w2  = (const float*)d_in[18];

  char* p = (char*)d_ws;
  auto alloc = [&](size_t bytes) -> char* {
    char* r = p;
    p += (bytes + 255) & ~(size_t)255;
    return r;
  };

  // bf16 weight pool
  u16* lin_b  = (u16*)alloc(65536 * 2);
  u16* ipw_b  = (u16*)alloc((size_t)2097152 * 2);
  u16* xpw_b  = (u16*)alloc((size_t)196608 * 2);
  u16* opw_b  = (u16*)alloc((size_t)1048576 * 2);
  u16* gupw_b = (u16*)alloc((size_t)8388608 * 2);
  u16* dpw_b  = (u16*)alloc((size_t)4194304 * 2);
  u16* hw1_b  = (u16*)alloc(65536 * 2);
  u16* hw2_b  = (u16*)alloc(8192 * 2);

  // activations
  u16* xT    = (u16*)alloc((size_t)kL * kDIM * 2);
  float* h   = (float*)alloc((size_t)kL * kDIM * 4);
  u16* hn    = (u16*)alloc((size_t)kL * kDIM * 2);
  u16* hb    = (u16*)alloc((size_t)kL * kDIM * 2);
  u16* hb2   = (u16*)alloc((size_t)kL * kDIM * 2);
  float* we  = (float*)alloc((size_t)kL * 4 * 4);
  float* xdbl = (float*)alloc((size_t)kL * 48 * 4);
  float* g2o  = (float*)alloc((size_t)kL * 32 * 4);
  u16* fb    = (u16*)alloc((size_t)kL * kDIM * 2);
  u16* h2b   = (u16*)alloc((size_t)kL * kDIM * 2);
  char* un   = alloc((size_t)67108864);  // xz bf16 (16MB) | gu bf16 (64MB)
  u16* xz    = (u16*)un;
  u16* gu    = (u16*)un;
  u16* ts    = (u16*)alloc((size_t)kL * 2048 * 2);
  u16* xcb   = (u16*)alloc((size_t)kL * kDI * 2);
  u16* zsb   = (u16*)alloc((size_t)kL * kDI * 2);
  u16* yv    = (u16*)alloc((size_t)kL * kDI * 2);
  float* delta = (float*)alloc((size_t)kL * kDI * 4);
  float* aprod = (float*)alloc((size_t)128 * 8192 * 4);
  float* bacc  = (float*)alloc((size_t)128 * 8192 * 4);
  float* sinit = (float*)alloc((size_t)128 * 8192 * 4);
  float* gp    = (float*)alloc((size_t)16 * 8192 * 4);
  float* gb    = (float*)alloc((size_t)16 * 8192 * 4);
  float* ginit = (float*)alloc((size_t)16 * 8192 * 4);
  float* moe   = (float*)alloc((size_t)kL * kDIM * 4);

  if ((size_t)(p - (char*)d_ws) > ws_size) return;  // fail loudly

  // ---- weight conversion ----
  CvtDescs dd;
  int seg = 0;
  auto add = [&](const float* s, u16* d, int n) { dd.s[seg] = s; dd.d[seg] = d; dd.n[seg] = n; ++seg; };
  add(lin_w, lin_b, 65536);
  add(in_proj, ipw_b, 2097152);
  add(x_proj, xpw_b, 196608);
  add(out_proj, opw_b, 1048576);
  add(head_w1, hw1_b, 65536);
  add(head_w2, hw2_b, 8192);
  for (int i = 0; i < kNB; ++i) {
    add(gproj + (size_t)i * 524288, gupw_b + (size_t)i * 1048576, 524288);
    add(uproj + (size_t)i * 524288, gupw_b + (size_t)i * 1048576 + 524288, 524288);
  }
  cvt_multi_k<<<dim3(64, 22), 256, 0, stream>>>(dd);
  cvt_dproj_k<<<2048, 256, 0, stream>>>(dproj, dpw_b);
  transpose_x_k<<<dim3(kL / 32, kDIM / 32), dim3(32, 8), 0, stream>>>(x, xT);

  // h = xT @ lin_w^T
  gemm_t<64, 128, 2, 4, 2, 0><<<dim3(128, 2, 1), 256, 0, stream>>>(xT, 256, lin_b, 256, h, 256, 256, 256);
  rms_a_k<<<kL, 256, 0, stream>>>(h, rms_a_w, hn);

  for (int i = 0; i < kNB; ++i) {
    // in_proj: N=1024, K=256 -> xz bf16
    gemm_t<128, 128, 4, 4, 2, 2><<<dim3(64, 8, 1), 256, 0, stream>>>(
        hn, 256, ipw_b + (size_t)i * 262144, 256, xz, 1024, 1024, 256);
    conv_silu_k<<<kL * kDI / 256, 256, 0, stream>>>(xz, conv_w + (size_t)i * 2048,
                                                    conv_b + (size_t)i * 512, xcb, zsb);
    // xdbl: N=48, K=512, split-K=8 atomic
    hipMemsetAsync(xdbl, 0, (size_t)kL * 48 * 4, stream);
    gemm_t<128, 48, 2, 3, 1, 4><<<dim3(64, 1, 8), 256, 0, stream>>>(
        xcb, 512, xpw_b + (size_t)i * 24576, 512, xdbl, 48, 48, 512);
    scan_a_k<<<dim3(128, 4), 256, 0, stream>>>(xdbl, xcb, A_log + (size_t)i * 8192,
                                               dt_w + (size_t)i * 8192, dt_b + (size_t)i * 512,
                                               delta, aprod, bacc);
    scan_b1_k<<<512, 256, 0, stream>>>(aprod, bacc, gp, gb);
    scan_b2_k<<<32, 256, 0, stream>>>(gp, gb, ginit);
    scan_b3_k<<<512, 256, 0, stream>>>(aprod, bacc, ginit, sinit);
    scan_c_k<<<dim3(128, 4), 256, 0, stream>>>(xdbl, xcb, zsb, A_log + (size_t)i * 8192,
                                               delta, sinit, D_param + (size_t)i * 512, yv);
    // out_proj: h += yv @ opw^T, split-K=4 atomic
    gemm_t<128, 128, 4, 4, 2, 4><<<dim3(64, 2, 4), 256, 0, stream>>>(
        yv, 512, opw_b + (size_t)i * 131072, 512, h, 256, 256, 512);
    router_k<<<kL / 4, 256, 0, stream>>>(h, gate_w + (size_t)i * 1024, we, hb);
    // merged g+u: N=4096, K=256
    gemm_t<128, 128, 4, 4, 2, 2><<<dim3(64, 32, 1), 256, 0, stream>>>(
        hb, 256, gupw_b + (size_t)i * 1048576, 256, gu, 4096, 4096, 256);
    mix_glu_k<<<kL * 2048 / 1024, 256, 0, stream>>>(gu, we, ts);
    // dproj: N=256, K=2048, split-K=4 atomic
    hipMemsetAsync(moe, 0, (size_t)kL * kDIM * 4, stream);
    gemm_t<128, 128, 4, 4, 2, 4><<<dim3(64, 2, 4), 256, 0, stream>>>(
        ts, 2048, dpw_b + (size_t)i * 524288, 2048, moe, 256, 256, 2048);
    rms_f_fused_k<<<kL, 256, 0, stream>>>(moe, rms_f_w, rms_a_w, h, hb2, hn);
  }

  // head
  gemm_t<64, 128, 2, 4, 2, 2><<<dim3(128, 2, 1), 256, 0, stream>>>(hb2, 256, lin_b, 256, h2b, 256, 256, 256);
  gemm_t<64, 128, 2, 4, 2, 3><<<dim3(128, 2, 1), 256, 0, stream>>>(h2b, 256, hw1_b, 256, fb, 256, 256, 256);
  gemm_t<64, 128, 2, 4, 2, 0><<<dim3(128, 1, 1), 256, 0, stream>>>(fb, 256, hw2_b, 256, g2o, 32, 32, 256);
  sig_t_k<<<kL / 32, 256, 0, stream>>>(g2o, (float*)d_out);
}

// Round 4
// 2155.519 us; speedup vs baseline: 1.2353x; 1.0532x over previous
//
#include <hip/hip_runtime.h>

typedef unsigned short u16;
typedef unsigned int u32;
using bf16x8 = __attribute__((ext_vector_type(8))) short;
using f32x4 = __attribute__((ext_vector_type(4))) float;

constexpr int kL = 8192;
constexpr int kDIM = 256;
constexpr int kDI = 512;
constexpr int kNB = 8;
constexpr float kEPS = 1e-3f;

__device__ __forceinline__ u16 f2b(float f) {
  u32 x = __builtin_bit_cast(u32, f);
  x += 0x7fffu + ((x >> 16) & 1u);
  return (u16)(x >> 16);
}
__device__ __forceinline__ float b2f(u16 u) {
  return __builtin_bit_cast(float, (u32)u << 16);
}
__device__ __forceinline__ float sigm(float x) { return 1.f / (1.f + __expf(-x)); }
__device__ __forceinline__ float softplus_fast(float x) {
  return fmaxf(x, 0.f) + __logf(1.f + __expf(-fabsf(x)));
}

__device__ __forceinline__ void async_cp16(const void* g, void* l) {
  __builtin_amdgcn_global_load_lds((const __attribute__((address_space(1))) u32*)g,
                                   (__attribute__((address_space(3))) u32*)l, 16, 0, 0);
}

// ---------------- balanced vectorized weight conversion ----------------
// mode 0: identity. mode 1: gu-interleave (src row j of 256 -> dst row 2j; dst ptr pre-offset for u).
// mode 2: dproj permute (NB,NE,DIM,INNER) -> (NB, DIM, NE*INNER).
struct Cvt2 {
  const float* s[23];
  u16* d[23];
  int n[23];
  int mode[23];
  int bstart[24];
  int nseg;
};
__global__ __launch_bounds__(256) void cvt2_k(Cvt2 dd) {
  const int b = blockIdx.x;
  int seg = 0;
  for (int i = 1; i < dd.nseg; ++i) seg += (b >= dd.bstart[i]) ? 1 : 0;
  const int lb = b - dd.bstart[seg];
  const float* s = dd.s[seg];
  u16* d = dd.d[seg];
  const int n = dd.n[seg];
  const int mode = dd.mode[seg];
  #pragma unroll
  for (int it = 0; it < 4; ++it) {
    const int e4 = lb * 1024 + it * 256 + threadIdx.x;
    const int i = e4 * 4;
    if (i >= n) break;
    const float4 v = ((const float4*)s)[e4];
    ushort4 o = make_ushort4(f2b(v.x), f2b(v.y), f2b(v.z), f2b(v.w));
    size_t dst;
    if (mode == 0) {
      dst = (size_t)i;
    } else if (mode == 1) {
      dst = (size_t)(((i >> 8) << 9) + (i & 255));
    } else {
      const int bb = i >> 19, e = (i >> 17) & 3, nr = (i >> 9) & 255, j = i & 511;
      dst = (size_t)bb * 524288 + (size_t)nr * 2048 + e * 512 + j;
    }
    *(ushort4*)&d[dst] = o;
  }
}

// x (DIM, L) f32 -> xT (L, DIM) bf16
__global__ __launch_bounds__(256) void transpose_x_k(const float* __restrict__ x, u16* __restrict__ xT) {
  __shared__ float tile[32][33];
  int l0 = blockIdx.x * 32, d0 = blockIdx.y * 32;
  int tx = threadIdx.x, ty = threadIdx.y;
  #pragma unroll
  for (int i = 0; i < 32; i += 8)
    tile[ty + i][tx] = x[(size_t)(d0 + ty + i) * kL + l0 + tx];
  __syncthreads();
  #pragma unroll
  for (int i = 0; i < 32; i += 8)
    xT[(size_t)(l0 + ty + i) * kDIM + d0 + tx] = f2b(tile[tx][ty + i]);
}

// ---------------- templated MFMA GEMM: C(MxN) = A(MxK) @ W(NxK)^T ----------------
// MODE 0: f32 store; 2: bf16 store; 3: silu->bf16; 4: f32 atomicAdd (split-K);
// MODE 5: f32 partial store at C + blockIdx.z*pstride (split-K, no atomics);
// MODE 6: GLU epilogue on gu-interleaved W (even col=g, odd col=u): ts = silu(g)*u*we, u16, ld 2048;
// MODE 7: sigmoid + transposed store: out[col*kL + row].
template <int BM, int BN, int TR, int TC, int WCN, int MODE>
__global__ __launch_bounds__(256) void gemm_t(
    const u16* __restrict__ A, int lda,
    const u16* __restrict__ W, int ldw,
    void* __restrict__ C, int ldc,
    int N, int K, const float* __restrict__ wep, int pstride)
{
  constexpr int BNR = (BN + 63) & ~63;
  __shared__ u16 As[BM * 64];
  __shared__ u16 Bs[BNR * 64];
  const int tid = threadIdx.x;
  const int lane = tid & 63;
  const int wave = tid >> 6;
  const int bm = blockIdx.x * BM;
  const int bn = blockIdx.y * BN;
  const int wrow = (wave / WCN) * (TR * 16);
  const int wcol = (wave % WCN) * (TC * 16);
  const int kchunk = K / (int)gridDim.z;
  const int kbeg = blockIdx.z * kchunk;
  const int kend = kbeg + kchunk;

  f32x4 acc[TR][TC];
  #pragma unroll
  for (int r = 0; r < TR; ++r)
    #pragma unroll
    for (int c = 0; c < TC; ++c)
      acc[r][c] = f32x4{0.f, 0.f, 0.f, 0.f};

  for (int k0 = kbeg; k0 < kend; k0 += 64) {
    #pragma unroll
    for (int it = 0; it < BM * 64 / 2048; ++it) {
      int flat = (it * 256 + tid) * 8;
      int r = flat >> 6;
      int gc = ((((flat >> 3) & 7) ^ (r & 7)) << 3);
      async_cp16(A + (size_t)(bm + r) * lda + k0 + gc, &As[flat]);
    }
    #pragma unroll
    for (int it = 0; it < BNR * 64 / 2048; ++it) {
      int flat = (it * 256 + tid) * 8;
      int r = flat >> 6;
      int gc = ((((flat >> 3) & 7) ^ (r & 7)) << 3);
      int n = bn + r;
      if (n > N - 1) n = N - 1;
      async_cp16(W + (size_t)n * ldw + k0 + gc, &Bs[flat]);
    }
    __syncthreads();
    const int mrow = lane & 15;
    #pragma unroll
    for (int kk = 0; kk < 64; kk += 32) {
      const int kc = (kk >> 3) + (lane >> 4);
      bf16x8 a[TR], b[TC];
      #pragma unroll
      for (int rr = 0; rr < TR; ++rr) {
        int row = wrow + rr * 16 + mrow;
        a[rr] = *(const bf16x8*)&As[row * 64 + ((kc ^ (row & 7)) << 3)];
      }
      #pragma unroll
      for (int cc = 0; cc < TC; ++cc) {
        int row = wcol + cc * 16 + mrow;
        b[cc] = *(const bf16x8*)&Bs[row * 64 + ((kc ^ (row & 7)) << 3)];
      }
      #pragma unroll
      for (int rr = 0; rr < TR; ++rr)
        #pragma unroll
        for (int cc = 0; cc < TC; ++cc)
          acc[rr][cc] = __builtin_amdgcn_mfma_f32_16x16x32_bf16(a[rr], b[cc], acc[rr][cc], 0, 0, 0);
    }
    __syncthreads();
  }

  const int colb = bn + wcol + (lane & 15);
  const int rowb = bm + wrow + ((lane >> 4) << 2);
  if constexpr (MODE == 6) {
    #pragma unroll
    for (int rr = 0; rr < TR; ++rr)
      #pragma unroll
      for (int cc = 0; cc < TC; ++cc) {
        const int col = colb + cc * 16;
        #pragma unroll
        for (int i = 0; i < 4; ++i) {
          const float v = acc[rr][cc][i];
          const float partner = __shfl_xor(v, 1);
          if (!(lane & 1)) {
            const int row = rowb + rr * 16 + i;
            const int tsj = col >> 1;
            const float w = wep[row * 4 + (tsj >> 9)];
            ((u16*)C)[(size_t)row * 2048 + tsj] = f2b(v * sigm(v) * partner * w);
          }
        }
      }
  } else {
    #pragma unroll
    for (int rr = 0; rr < TR; ++rr)
      #pragma unroll
      for (int cc = 0; cc < TC; ++cc) {
        int col = colb + cc * 16;
        if (col >= N) continue;
        #pragma unroll
        for (int i = 0; i < 4; ++i) {
          const int row = rowb + rr * 16 + i;
          size_t off = (size_t)row * ldc + col;
          float v = acc[rr][cc][i];
          if constexpr (MODE == 0) ((float*)C)[off] = v;
          else if constexpr (MODE == 2) ((u16*)C)[off] = f2b(v);
          else if constexpr (MODE == 3) ((u16*)C)[off] = f2b(v * sigm(v));
          else if constexpr (MODE == 4) atomicAdd(&((float*)C)[off], v);
          else if constexpr (MODE == 5) ((float*)C)[off + (size_t)blockIdx.z * pstride] = v;
          else if constexpr (MODE == 7) ((float*)C)[(size_t)col * kL + row] = sigm(v);
        }
      }
  }
}

// ---------------- block-wide sum over 256 threads ----------------
__device__ __forceinline__ float block_sum256(float v) {
  #pragma unroll
  for (int o = 32; o > 0; o >>= 1) v += __shfl_down(v, o);
  __shared__ float red[4];
  __syncthreads();
  if ((threadIdx.x & 63) == 0) red[threadIdx.x >> 6] = v;
  __syncthreads();
  return red[0] + red[1] + red[2] + red[3];
}

__global__ __launch_bounds__(256) void rms_a_k(const float* __restrict__ h, const float* __restrict__ w,
                                               u16* __restrict__ hn) {
  const int l = blockIdx.x, t = threadIdx.x;
  const float v = h[(size_t)l * kDIM + t];
  const float ssum = block_sum256(v * v);
  const float r = rsqrtf(ssum * (1.f / 256.f) + kEPS);
  hn[(size_t)l * kDIM + t] = f2b(w[t] * v * r);
}

// moe = sum of 4 dproj partials; h += rmsnorm_f(moe); emit hb2, hn(next rms_a)
__global__ __launch_bounds__(256) void rms_f_fused_k(const float* __restrict__ mpart,
                                                     const float* __restrict__ wf,
                                                     const float* __restrict__ wa,
                                                     float* __restrict__ h,
                                                     u16* __restrict__ hb2, u16* __restrict__ hn) {
  const int l = blockIdx.x, t = threadIdx.x;
  const size_t idx = (size_t)l * kDIM + t;
  const float m = mpart[idx] + mpart[idx + 2097152] + mpart[idx + 4194304] + mpart[idx + 6291456];
  const float r1 = rsqrtf(block_sum256(m * m) * (1.f / 256.f) + kEPS);
  const float hv = h[idx] + wf[t] * m * r1;
  h[idx] = hv;
  hb2[idx] = f2b(hv);
  const float r2 = rsqrtf(block_sum256(hv * hv) * (1.f / 256.f) + kEPS);
  hn[idx] = f2b(wa[t] * hv * r2);
}

// causal depthwise conv (4 taps, 4 channels/thread) + bias + silu -> xcb; z*silu(z) -> zsb;
// also zeroes xdbl for the split-K atomic GEMM that follows.
__global__ __launch_bounds__(256) void conv_silu_k(const u16* __restrict__ xz, const float* __restrict__ cw,
                                                   const float* __restrict__ cb,
                                                   u16* __restrict__ xcb, u16* __restrict__ zsb,
                                                   float* __restrict__ xdbl) {
  const int i4 = blockIdx.x * 256 + threadIdx.x;  // L*DI/4
  if (i4 < 98304) *(float4*)&xdbl[i4 * 4] = float4{0.f, 0.f, 0.f, 0.f};
  const int l = i4 >> 7;
  const int d = (i4 & 127) * 4;
  float acc[4];
  const float4 cbv = *(const float4*)&cb[d];
  acc[0] = cbv.x; acc[1] = cbv.y; acc[2] = cbv.z; acc[3] = cbv.w;
  #pragma unroll
  for (int j = 0; j < 4; ++j) {
    const int ll = l - 3 + j;
    if (ll >= 0) {
      const ushort4 xv = *(const ushort4*)&xz[(size_t)ll * 1024 + d];
      acc[0] += cw[(d + 0) * 4 + j] * b2f(xv.x);
      acc[1] += cw[(d + 1) * 4 + j] * b2f(xv.y);
      acc[2] += cw[(d + 2) * 4 + j] * b2f(xv.z);
      acc[3] += cw[(d + 3) * 4 + j] * b2f(xv.w);
    }
  }
  ushort4 xo, zo;
  const ushort4 zv = *(const ushort4*)&xz[(size_t)l * 1024 + 512 + d];
  float z0 = b2f(zv.x), z1 = b2f(zv.y), z2 = b2f(zv.z), z3 = b2f(zv.w);
  xo.x = f2b(acc[0] * sigm(acc[0])); xo.y = f2b(acc[1] * sigm(acc[1]));
  xo.z = f2b(acc[2] * sigm(acc[2])); xo.w = f2b(acc[3] * sigm(acc[3]));
  zo.x = f2b(z0 * sigm(z0)); zo.y = f2b(z1 * sigm(z1));
  zo.z = f2b(z2 * sigm(z2)); zo.w = f2b(z3 * sigm(z3));
  *(ushort4*)&xcb[(size_t)l * 512 + d] = xo;
  *(ushort4*)&zsb[(size_t)l * 512 + d] = zo;
}

// ---------------- chunked selective scan; lane-pair state split ----------------
__global__ __launch_bounds__(256) void scan_a_k(const float* __restrict__ xdbl, const u16* __restrict__ xcb,
                                                const float* __restrict__ A_log, const float* __restrict__ dtw,
                                                const float* __restrict__ dtb,
                                                u16* __restrict__ delta,
                                                float* __restrict__ aprod, float* __restrict__ bacc) {
  const int c = blockIdx.x;
  const int t = threadIdx.x;
  const int half = t & 1;
  const int d = blockIdx.y * 128 + (t >> 1);
  const int l0 = c * 64;
  __shared__ float Xs[64][32];  // [lr][0:16)=dr, [16:32)=B
  for (int i = t; i < 2048; i += 256)
    Xs[i >> 5][i & 31] = xdbl[(size_t)(l0 + (i >> 5)) * 48 + (i & 31)];
  __syncthreads();
  float wd[8], Ad[8];
  #pragma unroll
  for (int j = 0; j < 8; ++j) wd[j] = dtw[d * 16 + half * 8 + j];
  const float bd = dtb[d];
  #pragma unroll
  for (int n = 0; n < 8; ++n) Ad[n] = -__expf(A_log[d * 16 + half * 8 + n]);
  float s[8], ap[8];
  #pragma unroll
  for (int n = 0; n < 8; ++n) { s[n] = 0.f; ap[n] = 1.f; }
  #pragma unroll 4
  for (int lr = 0; lr < 64; ++lr) {
    const float4 dr0 = *(const float4*)&Xs[lr][half * 8];
    const float4 dr1 = *(const float4*)&Xs[lr][half * 8 + 4];
    float p0 = dr0.x * wd[0] + dr0.y * wd[1] + dr0.z * wd[2] + dr0.w * wd[3];
    float p1 = dr1.x * wd[4] + dr1.y * wd[5] + dr1.z * wd[6] + dr1.w * wd[7];
    float dot = p0 + p1;
    dot += __shfl_xor(dot, 1);
    const float dl = softplus_fast(dot + bd);
    const int l = l0 + lr;
    if (!half) delta[(size_t)l * 512 + d] = f2b(dl);
    const float du = dl * b2f(xcb[(size_t)l * 512 + d]);
    const float4 B0 = *(const float4*)&Xs[lr][16 + half * 8];
    const float4 B1 = *(const float4*)&Xs[lr][16 + half * 8 + 4];
    const float Bv[8] = {B0.x, B0.y, B0.z, B0.w, B1.x, B1.y, B1.z, B1.w};
    #pragma unroll
    for (int n = 0; n < 8; ++n) {
      const float a = __expf(dl * Ad[n]);
      s[n] = fmaf(a, s[n], du * Bv[n]);
      ap[n] *= a;
    }
  }
  const int base = c * 8192 + d * 16 + half * 8;
  #pragma unroll
  for (int n = 0; n < 8; ++n) { aprod[base + n] = ap[n]; bacc[base + n] = s[n]; }
}

// chunk combine, single kernel (32 blocks, 128 serial iters, software prefetch)
__global__ __launch_bounds__(256) void scan_b_k(const float* __restrict__ aprod, const float* __restrict__ bacc,
                                                float* __restrict__ sinit) {
  const int st = blockIdx.x * 256 + threadIdx.x;  // 8192 states
  float cur = 0.f;
  float a0 = aprod[st], b0 = bacc[st];
  for (int c = 0; c < 128; ++c) {
    float a1 = 0.f, b1 = 0.f;
    if (c + 1 < 128) {
      a1 = aprod[(size_t)(c + 1) * 8192 + st];
      b1 = bacc[(size_t)(c + 1) * 8192 + st];
    }
    sinit[(size_t)c * 8192 + st] = cur;
    cur = fmaf(a0, cur, b0);
    a0 = a1; b0 = b1;
  }
}

__global__ __launch_bounds__(256) void scan_c_k(const float* __restrict__ xdbl, const u16* __restrict__ xcb,
                                                const u16* __restrict__ zsb, const float* __restrict__ A_log,
                                                const u16* __restrict__ delta,
                                                const float* __restrict__ sinit,
                                                const float* __restrict__ Dp, u16* __restrict__ yv) {
  const int c = blockIdx.x;
  const int t = threadIdx.x;
  const int half = t & 1;
  const int d = blockIdx.y * 128 + (t >> 1);
  const int l0 = c * 64;
  __shared__ float Xs[64][32];  // [lr][0:16)=B, [16:32)=C
  for (int i = t; i < 2048; i += 256)
    Xs[i >> 5][i & 31] = xdbl[(size_t)(l0 + (i >> 5)) * 48 + 16 + (i & 31)];
  __syncthreads();
  float Ad[8];
  #pragma unroll
  for (int n = 0; n < 8; ++n) Ad[n] = -__expf(A_log[d * 16 + half * 8 + n]);
  float s[8];
  const int base = c * 8192 + d * 16 + half * 8;
  #pragma unroll
  for (int n = 0; n < 8; ++n) s[n] = sinit[base + n];
  const float Dd = Dp[d];
  #pragma unroll 4
  for (int lr = 0; lr < 64; ++lr) {
    const int l = l0 + lr;
    const float dl = b2f(delta[(size_t)l * 512 + d]);
    const float xv = b2f(xcb[(size_t)l * 512 + d]);
    const float zs = b2f(zsb[(size_t)l * 512 + d]);
    const float du = dl * xv;
    const float4 B0 = *(const float4*)&Xs[lr][half * 8];
    const float4 B1 = *(const float4*)&Xs[lr][half * 8 + 4];
    const float4 C0 = *(const float4*)&Xs[lr][16 + half * 8];
    const float4 C1 = *(const float4*)&Xs[lr][16 + half * 8 + 4];
    const float Bv[8] = {B0.x, B0.y, B0.z, B0.w, B1.x, B1.y, B1.z, B1.w};
    const float Cv[8] = {C0.x, C0.y, C0.z, C0.w, C1.x, C1.y, C1.z, C1.w};
    float y = 0.f;
    #pragma unroll
    for (int n = 0; n < 8; ++n) {
      const float a = __expf(dl * Ad[n]);
      s[n] = fmaf(a, s[n], du * Bv[n]);
      y = fmaf(s[n], Cv[n], y);
    }
    y += __shfl_xor(y, 1);
    if (!half) yv[(size_t)l * 512 + d] = f2b((y + xv * Dd) * zs);
  }
}

// router: h = h_old + sum(4 out_proj partials); top-2 softmax weights; bf16 copy of h
__global__ __launch_bounds__(256) void router_k(float* __restrict__ h, const float* __restrict__ hpart,
                                                const float* __restrict__ gw,
                                                float* __restrict__ we, u16* __restrict__ hb) {
  const int l = blockIdx.x * 4 + (threadIdx.x >> 6);
  const int lane = threadIdx.x & 63;
  const size_t ro = (size_t)l * 256;
  float4 v = reinterpret_cast<const float4*>(h + ro)[lane];
  #pragma unroll
  for (int z = 0; z < 4; ++z) {
    const float4 pv = reinterpret_cast<const float4*>(hpart + (size_t)z * 2097152 + ro)[lane];
    v.x += pv.x; v.y += pv.y; v.z += pv.z; v.w += pv.w;
  }
  reinterpret_cast<float4*>(h + ro)[lane] = v;
  reinterpret_cast<ushort4*>(hb + ro)[lane] = make_ushort4(f2b(v.x), f2b(v.y), f2b(v.z), f2b(v.w));
  float p[4];
  #pragma unroll
  for (int e = 0; e < 4; ++e) {
    const float4 g = reinterpret_cast<const float4*>(gw + (size_t)e * 256)[lane];
    p[e] = v.x * g.x + v.y * g.y + v.z * g.z + v.w * g.w;
  }
  #pragma unroll
  for (int o = 32; o > 0; o >>= 1) {
    p[0] += __shfl_down(p[0], o);
    p[1] += __shfl_down(p[1], o);
    p[2] += __shfl_down(p[2], o);
    p[3] += __shfl_down(p[3], o);
  }
  if (lane == 0) {
    int i0 = 0;
    #pragma unroll
    for (int e = 1; e < 4; ++e) if (p[e] > p[i0]) i0 = e;
    int i1 = -1;
    #pragma unroll
    for (int e = 0; e < 4; ++e) {
      if (e == i0) continue;
      if (i1 < 0 || p[e] > p[i1]) i1 = e;
    }
    const float tt = __expf(p[i1] - p[i0]);
    const float w0 = 1.f / (1.f + tt);
    const float w1 = tt / (1.f + tt);
    float o[4] = {0.f, 0.f, 0.f, 0.f};
    o[i0] = w0; o[i1] = w1;
    reinterpret_cast<float4*>(we)[l] = make_float4(o[0], o[1], o[2], o[3]);
  }
}

extern "C" void kernel_launch(void* const* d_in, const int* in_sizes, int n_in,
                              void* d_out, int out_size, void* d_ws, size_t ws_size,
                              hipStream_t stream) {
  const float* x        = (const float*)d_in[0];
  const float* lin_w    = (const float*)d_in[1];
  const float* in_proj  = (const float*)d_in[2];
  const float* conv_w   = (const float*)d_in[3];
  const float* conv_b   = (const float*)d_in[4];
  const float* x_proj   = (const float*)d_in[5];
  const float* dt_w     = (const float*)d_in[6];
  const float* dt_b     = (const float*)d_in[7];
  const float* A_log    = (const float*)d_in[8];
  const float* D_param  = (const float*)d_in[9];
  const float* out_proj = (const float*)d_in[10];
  const float* gate_w   = (const float*)d_in[11];
  const float* gproj    = (const float*)d_in[12];
  const float* uproj    = (const float*)d_in[13];
  const float* dproj    = (const float*)d_in[14];
  const float* rms_a_w  = (const float*)d_in[15];
  const float* rms_f_w  = (const float*)d_in[16];
  const float* head_w1  = (const float*)d_in[17];
  const float* head_w2  = (const float*)d_in[18];

  char* p = (char*)d_ws;
  auto alloc = [&](size_t bytes) -> char* {
    char* r = p;
    p += (bytes + 255) & ~(size_t)255;
    return r;
  };

  // bf16 weight pool
  u16* lin_b  = (u16*)alloc(65536 * 2);
  u16* ipw_b  = (u16*)alloc((size_t)2097152 * 2);
  u16* xpw_b  = (u16*)alloc((size_t)196608 * 2);
  u16* opw_b  = (u16*)alloc((size_t)1048576 * 2);
  u16* gupw_b = (u16*)alloc((size_t)8388608 * 2);  // gu-interleaved rows
  u16* dpw_b  = (u16*)alloc((size_t)4194304 * 2);
  u16* hw1_b  = (u16*)alloc(65536 * 2);
  u16* hw2_b  = (u16*)alloc(8192 * 2);

  // activations
  u16* xT     = (u16*)alloc((size_t)kL * kDIM * 2);
  float* h    = (float*)alloc((size_t)kL * kDIM * 4);
  u16* hn     = (u16*)alloc((size_t)kL * kDIM * 2);
  u16* hb     = (u16*)alloc((size_t)kL * kDIM * 2);
  u16* hb2    = (u16*)alloc((size_t)kL * kDIM * 2);
  float* we   = (float*)alloc((size_t)kL * 4 * 4);
  float* xdbl = (float*)alloc((size_t)kL * 48 * 4);
  u16* fb     = (u16*)alloc((size_t)kL * kDIM * 2);
  u16* h2b    = (u16*)alloc((size_t)kL * kDIM * 2);
  u16* xz     = (u16*)alloc((size_t)kL * 1024 * 2);
  u16* ts     = (u16*)alloc((size_t)kL * 2048 * 2);
  u16* xcb    = (u16*)alloc((size_t)kL * kDI * 2);
  u16* zsb    = (u16*)alloc((size_t)kL * kDI * 2);
  u16* yv     = (u16*)alloc((size_t)kL * kDI * 2);
  u16* delta  = (u16*)alloc((size_t)kL * kDI * 2);
  float* aprod = (float*)alloc((size_t)128 * 8192 * 4);
  float* bacc  = (float*)alloc((size_t)128 * 8192 * 4);
  float* sinit = (float*)alloc((size_t)128 * 8192 * 4);
  float* hpart = (float*)alloc((size_t)4 * kL * kDIM * 4);
  float* mpart = (float*)alloc((size_t)4 * kL * kDIM * 4);

  if ((size_t)(p - (char*)d_ws) > ws_size) return;  // fail loudly

  // ---- weight conversion: one balanced launch ----
  Cvt2 dd;
  int seg = 0, blk = 0;
  auto add = [&](const float* s, u16* d, int n, int mode) {
    dd.s[seg] = s; dd.d[seg] = d; dd.n[seg] = n; dd.mode[seg] = mode;
    dd.bstart[seg] = blk;
    blk += (n + 4095) / 4096;
    ++seg;
  };
  add(lin_w, lin_b, 65536, 0);
  add(in_proj, ipw_b, 2097152, 0);
  add(x_proj, xpw_b, 196608, 0);
  add(out_proj, opw_b, 1048576, 0);
  add(head_w1, hw1_b, 65536, 0);
  add(head_w2, hw2_b, 8192, 0);
  for (int i = 0; i < kNB; ++i) {
    add(gproj + (size_t)i * 524288, gupw_b + (size_t)i * 1048576, 524288, 1);
    add(uproj + (size_t)i * 524288, gupw_b + (size_t)i * 1048576 + 256, 524288, 1);
  }
  add(dproj, dpw_b, 4194304, 2);
  dd.nseg = seg;
  dd.bstart[seg] = blk;
  cvt2_k<<<blk, 256, 0, stream>>>(dd);
  transpose_x_k<<<dim3(kL / 32, kDIM / 32), dim3(32, 8), 0, stream>>>(x, xT);

  // h = xT @ lin_w^T
  gemm_t<64, 128, 2, 4, 2, 0><<<dim3(128, 2, 1), 256, 0, stream>>>(
      xT, 256, lin_b, 256, h, 256, 256, 256, nullptr, 0);
  rms_a_k<<<kL, 256, 0, stream>>>(h, rms_a_w, hn);

  for (int i = 0; i < kNB; ++i) {
    // in_proj: N=1024, K=256 -> xz bf16
    gemm_t<128, 128, 4, 4, 2, 2><<<dim3(64, 8, 1), 256, 0, stream>>>(
        hn, 256, ipw_b + (size_t)i * 262144, 256, xz, 1024, 1024, 256, nullptr, 0);
    conv_silu_k<<<kL * kDI / 1024, 256, 0, stream>>>(xz, conv_w + (size_t)i * 2048,
                                                     conv_b + (size_t)i * 512, xcb, zsb, xdbl);
    // xdbl: N=48, K=512, split-K=8 atomic (xdbl zeroed by conv kernel)
    gemm_t<128, 48, 2, 3, 1, 4><<<dim3(64, 1, 8), 256, 0, stream>>>(
        xcb, 512, xpw_b + (size_t)i * 24576, 512, xdbl, 48, 48, 512, nullptr, 0);
    scan_a_k<<<dim3(128, 4), 256, 0, stream>>>(xdbl, xcb, A_log + (size_t)i * 8192,
                                               dt_w + (size_t)i * 8192, dt_b + (size_t)i * 512,
                                               delta, aprod, bacc);
    scan_b_k<<<32, 256, 0, stream>>>(aprod, bacc, sinit);
    scan_c_k<<<dim3(128, 4), 256, 0, stream>>>(xdbl, xcb, zsb, A_log + (size_t)i * 8192,
                                               delta, sinit, D_param + (size_t)i * 512, yv);
    // out_proj: split-K=4 -> 4 partial buffers (reduced in router)
    gemm_t<128, 128, 4, 4, 2, 5><<<dim3(64, 2, 4), 256, 0, stream>>>(
        yv, 512, opw_b + (size_t)i * 131072, 512, hpart, 256, 256, 512, nullptr, 2097152);
    router_k<<<kL / 4, 256, 0, stream>>>(h, hpart, gate_w + (size_t)i * 1024, we, hb);
    // merged g+u with fused GLU epilogue: N=4096 interleaved, writes ts directly
    gemm_t<128, 128, 4, 4, 2, 6><<<dim3(64, 32, 1), 256, 0, stream>>>(
        hb, 256, gupw_b + (size_t)i * 1048576, 256, ts, 2048, 4096, 256, we, 0);
    // dproj: N=256, K=2048, split-K=4 -> 4 partial buffers (reduced in rms_f)
    gemm_t<128, 128, 4, 4, 2, 5><<<dim3(64, 2, 4), 256, 0, stream>>>(
        ts, 2048, dpw_b + (size_t)i * 524288, 2048, mpart, 256, 256, 2048, nullptr, 2097152);
    rms_f_fused_k<<<kL, 256, 0, stream>>>(mpart, rms_f_w, rms_a_w, h, hb2, hn);
  }

  // head: lin -> silu(head1) -> head2 + sigmoid-transpose fused
  gemm_t<64, 128, 2, 4, 2, 2><<<dim3(128, 2, 1), 256, 0, stream>>>(
      hb2, 256, lin_b, 256, h2b, 256, 256, 256, nullptr, 0);
  gemm_t<64, 128, 2, 4, 2, 3><<<dim3(128, 2, 1), 256, 0, stream>>>(
      h2b, 256, hw1_b, 256, fb, 256, 256, 256, nullptr, 0);
  gemm_t<64, 128, 2, 4, 2, 7><<<dim3(128, 1, 1), 256, 0, stream>>>(
      fb, 256, hw2_b, 256, (float*)d_out, 32, 32, 256, nullptr, 0);
}

// Round 5
// 2146.510 us; speedup vs baseline: 1.2405x; 1.0042x over previous
//
#include <hip/hip_runtime.h>

typedef unsigned short u16;
typedef unsigned int u32;
using bf16x8 = __attribute__((ext_vector_type(8))) short;
using f32x4 = __attribute__((ext_vector_type(4))) float;

constexpr int kL = 8192;
constexpr int kDIM = 256;
constexpr int kDI = 512;
constexpr int kNB = 8;
constexpr float kEPS = 1e-3f;

__device__ __forceinline__ u16 f2b(float f) {
  u32 x = __builtin_bit_cast(u32, f);
  x += 0x7fffu + ((x >> 16) & 1u);
  return (u16)(x >> 16);
}
__device__ __forceinline__ float b2f(u16 u) {
  return __builtin_bit_cast(float, (u32)u << 16);
}
__device__ __forceinline__ float sigm(float x) { return 1.f / (1.f + __expf(-x)); }
__device__ __forceinline__ float softplus_fast(float x) {
  return fmaxf(x, 0.f) + __logf(1.f + __expf(-fabsf(x)));
}

__device__ __forceinline__ void async_cp16(const void* g, void* l) {
  __builtin_amdgcn_global_load_lds((const __attribute__((address_space(1))) u32*)g,
                                   (__attribute__((address_space(3))) u32*)l, 16, 0, 0);
}

// ---------------- balanced vectorized weight conversion ----------------
// mode 0: identity.
// mode 1: gu 16-wide interleave with expert grouping:
//   src row (e*512 + j) -> dst row e*1024 + (j>>4)*32 + (j&15)  (u: dst ptr pre-offset +16 rows)
// mode 2: dproj permute (NB,NE,DIM,INNER) -> (NB, DIM, NE*INNER).
struct Cvt2 {
  const float* s[23];
  u16* d[23];
  int n[23];
  int mode[23];
  int bstart[24];
  int nseg;
};
__global__ __launch_bounds__(256) void cvt2_k(Cvt2 dd) {
  const int b = blockIdx.x;
  int seg = 0;
  for (int i = 1; i < dd.nseg; ++i) seg += (b >= dd.bstart[i]) ? 1 : 0;
  const int lb = b - dd.bstart[seg];
  const float* s = dd.s[seg];
  u16* d = dd.d[seg];
  const int n = dd.n[seg];
  const int mode = dd.mode[seg];
  #pragma unroll
  for (int it = 0; it < 4; ++it) {
    const int e4 = lb * 1024 + it * 256 + threadIdx.x;
    const int i = e4 * 4;
    if (i >= n) break;
    const float4 v = ((const float4*)s)[e4];
    ushort4 o = make_ushort4(f2b(v.x), f2b(v.y), f2b(v.z), f2b(v.w));
    size_t dst;
    if (mode == 0) {
      dst = (size_t)i;
    } else if (mode == 1) {
      const int row = i >> 8, col = i & 255;
      const int drow = (row >> 9) * 1024 + ((row >> 4) & 31) * 32 + (row & 15);
      dst = (size_t)drow * 256 + col;
    } else {
      const int bb = i >> 19, e = (i >> 17) & 3, nr = (i >> 9) & 255, j = i & 511;
      dst = (size_t)bb * 524288 + (size_t)nr * 2048 + e * 512 + j;
    }
    *(ushort4*)&d[dst] = o;
  }
}

// x (DIM, L) f32 -> xT (L, DIM) bf16
__global__ __launch_bounds__(256) void transpose_x_k(const float* __restrict__ x, u16* __restrict__ xT) {
  __shared__ float tile[32][33];
  int l0 = blockIdx.x * 32, d0 = blockIdx.y * 32;
  int tx = threadIdx.x, ty = threadIdx.y;
  #pragma unroll
  for (int i = 0; i < 32; i += 8)
    tile[ty + i][tx] = x[(size_t)(d0 + ty + i) * kL + l0 + tx];
  __syncthreads();
  #pragma unroll
  for (int i = 0; i < 32; i += 8)
    xT[(size_t)(l0 + ty + i) * kDIM + d0 + tx] = f2b(tile[tx][ty + i]);
}

// ---------------- templated MFMA GEMM: C(MxN) = A(MxK) @ W(NxK)^T ----------------
// MODE 0: f32 store; 2: bf16 store; 3: silu->bf16; 4: f32 atomicAdd (split-K);
// MODE 5: f32 partial store at C + blockIdx.z*pstride; MODE 7: sigmoid + transposed store.
template <int BM, int BN, int TR, int TC, int WCN, int MODE>
__global__ __launch_bounds__(256) void gemm_t(
    const u16* __restrict__ A, int lda,
    const u16* __restrict__ W, int ldw,
    void* __restrict__ C, int ldc,
    int N, int K, int pstride)
{
  constexpr int BNR = (BN + 63) & ~63;
  __shared__ u16 As[BM * 64];
  __shared__ u16 Bs[BNR * 64];
  const int tid = threadIdx.x;
  const int lane = tid & 63;
  const int wave = tid >> 6;
  const int bm = blockIdx.x * BM;
  const int bn = blockIdx.y * BN;
  const int wrow = (wave / WCN) * (TR * 16);
  const int wcol = (wave % WCN) * (TC * 16);
  const int kchunk = K / (int)gridDim.z;
  const int kbeg = blockIdx.z * kchunk;
  const int kend = kbeg + kchunk;

  f32x4 acc[TR][TC];
  #pragma unroll
  for (int r = 0; r < TR; ++r)
    #pragma unroll
    for (int c = 0; c < TC; ++c)
      acc[r][c] = f32x4{0.f, 0.f, 0.f, 0.f};

  for (int k0 = kbeg; k0 < kend; k0 += 64) {
    #pragma unroll
    for (int it = 0; it < BM * 64 / 2048; ++it) {
      int flat = (it * 256 + tid) * 8;
      int r = flat >> 6;
      int gc = ((((flat >> 3) & 7) ^ (r & 7)) << 3);
      async_cp16(A + (size_t)(bm + r) * lda + k0 + gc, &As[flat]);
    }
    #pragma unroll
    for (int it = 0; it < BNR * 64 / 2048; ++it) {
      int flat = (it * 256 + tid) * 8;
      int r = flat >> 6;
      int gc = ((((flat >> 3) & 7) ^ (r & 7)) << 3);
      int n = bn + r;
      if (n > N - 1) n = N - 1;
      async_cp16(W + (size_t)n * ldw + k0 + gc, &Bs[flat]);
    }
    __syncthreads();
    #pragma unroll
    for (int kk = 0; kk < 64; kk += 32) {
      const int kc = (kk >> 3) + (lane >> 4);
      const int mrow = lane & 15;
      bf16x8 a[TR], b[TC];
      #pragma unroll
      for (int rr = 0; rr < TR; ++rr) {
        int row = wrow + rr * 16 + mrow;
        a[rr] = *(const bf16x8*)&As[row * 64 + ((kc ^ (row & 7)) << 3)];
      }
      #pragma unroll
      for (int cc = 0; cc < TC; ++cc) {
        int row = wcol + cc * 16 + mrow;
        b[cc] = *(const bf16x8*)&Bs[row * 64 + ((kc ^ (row & 7)) << 3)];
      }
      #pragma unroll
      for (int rr = 0; rr < TR; ++rr)
        #pragma unroll
        for (int cc = 0; cc < TC; ++cc)
          acc[rr][cc] = __builtin_amdgcn_mfma_f32_16x16x32_bf16(a[rr], b[cc], acc[rr][cc], 0, 0, 0);
    }
    __syncthreads();
  }

  const int colb = bn + wcol + (lane & 15);
  const int rowb = bm + wrow + ((lane >> 4) << 2);
  #pragma unroll
  for (int rr = 0; rr < TR; ++rr)
    #pragma unroll
    for (int cc = 0; cc < TC; ++cc) {
      int col = colb + cc * 16;
      if (col >= N) continue;
      #pragma unroll
      for (int i = 0; i < 4; ++i) {
        const int row = rowb + rr * 16 + i;
        size_t off = (size_t)row * ldc + col;
        float v = acc[rr][cc][i];
        if constexpr (MODE == 0) ((float*)C)[off] = v;
        else if constexpr (MODE == 2) ((u16*)C)[off] = f2b(v);
        else if constexpr (MODE == 3) ((u16*)C)[off] = f2b(v * sigm(v));
        else if constexpr (MODE == 4) atomicAdd(&((float*)C)[off], v);
        else if constexpr (MODE == 5) ((float*)C)[off + (size_t)blockIdx.z * pstride] = v;
        else if constexpr (MODE == 7) ((float*)C)[(size_t)col * kL + row] = sigm(v);
      }
    }
}

// ---------------- fused MoE mega-kernel ----------------
// 256 blocks x 512 threads. Block owns 32 rows of h.
// phase -1: hv = h + sum(hpart); router top2 -> WeS; Ah = bf16(hv) in LDS.
// phase 1 (per expert, per 256-col chunk): gu GEMM (K=256) from Ah + staged W; GLU mix -> Ts (LDS).
// phase 2 (per expert): moeacc += Ts @ dpw_e^T (K=512).
// epilogue: rms_f + residual + rms_a, write h, hb2, hn.
__global__ __launch_bounds__(512, 1) void moe_mega_k(
    float* __restrict__ h, const float* __restrict__ hpart,
    const float* __restrict__ gw,
    const u16* __restrict__ Wgu, const u16* __restrict__ Wd,
    const float* __restrict__ wf, const float* __restrict__ wa,
    u16* __restrict__ hb2, u16* __restrict__ hn)
{
  __shared__ u16 Ah[32 * 256];       // 16 KB, swizzled: LDS[r][c] = src[r][c ^ (r&7)] (16B chunks)
  __shared__ u16 Ts[32 * 512];       // 32 KB, swizzled
  __shared__ u16 Ws[2][256 * 64];    // 64 KB staging, swizzled
  __shared__ float WeS[32][4];
  const int tid = threadIdx.x;
  const int lane = tid & 63;
  const int quad = lane >> 4;
  const int m16 = lane & 15;
  const int wave = tid >> 6;         // 0..7
  const int wcol = wave * 32;
  const int r0 = blockIdx.x * 32;
  const int prow = tid >> 4;         // 0..31
  const int pcol = (tid & 15) * 16;

  // ---- phase -1 ----
  float hv[16];
  {
    const size_t base = (size_t)(r0 + prow) * 256 + pcol;
    #pragma unroll
    for (int j = 0; j < 16; j += 4) {
      float4 v = *(const float4*)(h + base + j);
      #pragma unroll
      for (int z = 0; z < 4; ++z) {
        const float4 pv = *(const float4*)(hpart + (size_t)z * 2097152 + base + j);
        v.x += pv.x; v.y += pv.y; v.z += pv.z; v.w += pv.w;
      }
      hv[j] = v.x; hv[j + 1] = v.y; hv[j + 2] = v.z; hv[j + 3] = v.w;
    }
  }
  {
    float p[4];
    #pragma unroll
    for (int e = 0; e < 4; ++e) {
      float s = 0.f;
      #pragma unroll
      for (int j = 0; j < 16; ++j) s += hv[j] * gw[e * 256 + pcol + j];
      p[e] = s;
    }
    #pragma unroll
    for (int o = 8; o > 0; o >>= 1) {
      p[0] += __shfl_xor(p[0], o); p[1] += __shfl_xor(p[1], o);
      p[2] += __shfl_xor(p[2], o); p[3] += __shfl_xor(p[3], o);
    }
    if ((tid & 15) == 0) {
      int i0 = 0;
      #pragma unroll
      for (int e = 1; e < 4; ++e) if (p[e] > p[i0]) i0 = e;
      int i1 = -1;
      #pragma unroll
      for (int e = 0; e < 4; ++e) {
        if (e == i0) continue;
        if (i1 < 0 || p[e] > p[i1]) i1 = e;
      }
      const float tt = __expf(p[i1] - p[i0]);
      float o0 = 1.f / (1.f + tt), o1 = tt / (1.f + tt);
      WeS[prow][0] = 0.f; WeS[prow][1] = 0.f; WeS[prow][2] = 0.f; WeS[prow][3] = 0.f;
      WeS[prow][i0] = o0; WeS[prow][i1] = o1;
    }
    // Ah store
    #pragma unroll
    for (int cc = 0; cc < 2; ++cc) {
      const int chunk = (pcol >> 3) + cc;
      const int sw = ((chunk ^ (prow & 7)) << 3);
      u16 tmp[8];
      #pragma unroll
      for (int j = 0; j < 8; ++j) tmp[j] = f2b(hv[cc * 8 + j]);
      *(bf16x8*)&Ah[prow * 256 + sw] = *(bf16x8*)tmp;
    }
  }
  __syncthreads();

  f32x4 macc[2][2];
  #pragma unroll
  for (int rt = 0; rt < 2; ++rt)
    #pragma unroll
    for (int ct = 0; ct < 2; ++ct) macc[rt][ct] = f32x4{0.f, 0.f, 0.f, 0.f};

  auto stage_gu = [&](int buf, int e, int nc, int k0) {
    #pragma unroll
    for (int it = 0; it < 4; ++it) {
      const int flat = (it * 512 + tid) * 8;
      const int r = flat >> 6;
      const int gc = ((((flat >> 3) & 7) ^ (r & 7)) << 3);
      async_cp16(Wgu + (size_t)(e * 1024 + nc * 256 + r) * 256 + k0 + gc, &Ws[buf][flat]);
    }
  };
  auto stage_dp = [&](int buf, int e, int k0) {
    #pragma unroll
    for (int it = 0; it < 4; ++it) {
      const int flat = (it * 512 + tid) * 8;
      const int r = flat >> 6;
      const int gc = ((((flat >> 3) & 7) ^ (r & 7)) << 3);
      async_cp16(Wd + (size_t)r * 2048 + e * 512 + k0 + gc, &Ws[buf][flat]);
    }
  };

  for (int e = 0; e < 4; ++e) {
    // ---- phase 1 ----
    for (int nc = 0; nc < 4; ++nc) {
      f32x4 acc[2][2];
      #pragma unroll
      for (int rt = 0; rt < 2; ++rt)
        #pragma unroll
        for (int ct = 0; ct < 2; ++ct) acc[rt][ct] = f32x4{0.f, 0.f, 0.f, 0.f};
      stage_gu(0, e, nc, 0);
      __syncthreads();
      #pragma unroll
      for (int k0i = 0; k0i < 4; ++k0i) {
        if (k0i < 3) stage_gu((k0i + 1) & 1, e, nc, (k0i + 1) * 64);
        const u16* buf = Ws[k0i & 1];
        #pragma unroll
        for (int kk = 0; kk < 64; kk += 32) {
          const int kcs = (kk >> 3) + quad;
          bf16x8 a[2], b[2];
          #pragma unroll
          for (int rt = 0; rt < 2; ++rt) {
            const int row = rt * 16 + m16;
            const int ch = ((k0i * 64 + kk) >> 3) + quad;
            a[rt] = *(const bf16x8*)&Ah[row * 256 + ((ch ^ (row & 7)) << 3)];
          }
          #pragma unroll
          for (int ct = 0; ct < 2; ++ct) {
            const int n = wcol + ct * 16 + m16;
            b[ct] = *(const bf16x8*)&buf[n * 64 + ((kcs ^ (n & 7)) << 3)];
          }
          #pragma unroll
          for (int rt = 0; rt < 2; ++rt)
            #pragma unroll
            for (int ct = 0; ct < 2; ++ct)
              acc[rt][ct] = __builtin_amdgcn_mfma_f32_16x16x32_bf16(a[rt], b[ct], acc[rt][ct], 0, 0, 0);
        }
        __syncthreads();
      }
      // GLU mix -> Ts (g = acc[rt][0], u = acc[rt][1], same lane holds matching pair)
      const int group = nc * 8 + wave;
      const int j = group * 16 + m16;
      #pragma unroll
      for (int rt = 0; rt < 2; ++rt)
        #pragma unroll
        for (int i = 0; i < 4; ++i) {
          const int row = rt * 16 + quad * 4 + i;
          const float g = acc[rt][0][i];
          const float u = acc[rt][1][i];
          const float val = g * sigm(g) * u * WeS[row][e];
          Ts[row * 512 + (((j >> 3) ^ (row & 7)) << 3) + (j & 7)] = f2b(val);
        }
    }
    __syncthreads();  // Ts complete
    // ---- phase 2 ----
    stage_dp(0, e, 0);
    __syncthreads();
    #pragma unroll
    for (int k0i = 0; k0i < 8; ++k0i) {
      if (k0i < 7) stage_dp((k0i + 1) & 1, e, (k0i + 1) * 64);
      const u16* buf = Ws[k0i & 1];
      #pragma unroll
      for (int kk = 0; kk < 64; kk += 32) {
        const int kcs = (kk >> 3) + quad;
        bf16x8 a[2], b[2];
        #pragma unroll
        for (int rt = 0; rt < 2; ++rt) {
          const int row = rt * 16 + m16;
          const int ch = ((k0i * 64 + kk) >> 3) + quad;
          a[rt] = *(const bf16x8*)&Ts[row * 512 + ((ch ^ (row & 7)) << 3)];
        }
        #pragma unroll
        for (int ct = 0; ct < 2; ++ct) {
          const int n = wcol + ct * 16 + m16;
          b[ct] = *(const bf16x8*)&buf[n * 64 + ((kcs ^ (n & 7)) << 3)];
        }
        #pragma unroll
        for (int rt = 0; rt < 2; ++rt)
          #pragma unroll
          for (int ct = 0; ct < 2; ++ct)
            macc[rt][ct] = __builtin_amdgcn_mfma_f32_16x16x32_bf16(a[rt], b[ct], macc[rt][ct], 0, 0, 0);
      }
      __syncthreads();
    }
  }

  // ---- epilogue: moeacc -> LDS (row-major), dual rmsnorm, stores ----
  float* MoeS = (float*)Ts;  // 32x256 f32 = 32 KB overlay
  __syncthreads();
  #pragma unroll
  for (int rt = 0; rt < 2; ++rt)
    #pragma unroll
    for (int ct = 0; ct < 2; ++ct)
      #pragma unroll
      for (int i = 0; i < 4; ++i)
        MoeS[(rt * 16 + quad * 4 + i) * 256 + wcol + ct * 16 + m16] = macc[rt][ct][i];
  __syncthreads();

  float mv[16];
  float ss = 0.f;
  #pragma unroll
  for (int j = 0; j < 16; ++j) {
    mv[j] = MoeS[prow * 256 + pcol + j];
    ss += mv[j] * mv[j];
  }
  #pragma unroll
  for (int o = 8; o > 0; o >>= 1) ss += __shfl_xor(ss, o);
  const float r1 = rsqrtf(ss * (1.f / 256.f) + kEPS);
  float ss2 = 0.f;
  #pragma unroll
  for (int j = 0; j < 16; ++j) {
    hv[j] += wf[pcol + j] * mv[j] * r1;
    ss2 += hv[j] * hv[j];
  }
  #pragma unroll
  for (int o = 8; o > 0; o >>= 1) ss2 += __shfl_xor(ss2, o);
  const float r2 = rsqrtf(ss2 * (1.f / 256.f) + kEPS);

  const size_t base = (size_t)(r0 + prow) * 256 + pcol;
  #pragma unroll
  for (int j = 0; j < 16; j += 4)
    *(float4*)(h + base + j) = float4{hv[j], hv[j + 1], hv[j + 2], hv[j + 3]};
  #pragma unroll
  for (int j = 0; j < 16; j += 4) {
    *(ushort4*)(hb2 + base + j) = make_ushort4(f2b(hv[j]), f2b(hv[j + 1]), f2b(hv[j + 2]), f2b(hv[j + 3]));
    *(ushort4*)(hn + base + j) = make_ushort4(
        f2b(wa[pcol + j] * hv[j] * r2), f2b(wa[pcol + j + 1] * hv[j + 1] * r2),
        f2b(wa[pcol + j + 2] * hv[j + 2] * r2), f2b(wa[pcol + j + 3] * hv[j + 3] * r2));
  }
}

// ---------------- block-wide sum over 256 threads ----------------
__device__ __forceinline__ float block_sum256(float v) {
  #pragma unroll
  for (int o = 32; o > 0; o >>= 1) v += __shfl_down(v, o);
  __shared__ float red[4];
  __syncthreads();
  if ((threadIdx.x & 63) == 0) red[threadIdx.x >> 6] = v;
  __syncthreads();
  return red[0] + red[1] + red[2] + red[3];
}

__global__ __launch_bounds__(256) void rms_a_k(const float* __restrict__ h, const float* __restrict__ w,
                                               u16* __restrict__ hn) {
  const int l = blockIdx.x, t = threadIdx.x;
  const float v = h[(size_t)l * kDIM + t];
  const float ssum = block_sum256(v * v);
  const float r = rsqrtf(ssum * (1.f / 256.f) + kEPS);
  hn[(size_t)l * kDIM + t] = f2b(w[t] * v * r);
}

// causal depthwise conv (4 taps, 4 channels/thread) + bias + silu -> xcb; z*silu(z) -> zsb;
// also zeroes xdbl for the split-K atomic GEMM that follows.
__global__ __launch_bounds__(256) void conv_silu_k(const u16* __restrict__ xz, const float* __restrict__ cw,
                                                   const float* __restrict__ cb,
                                                   u16* __restrict__ xcb, u16* __restrict__ zsb,
                                                   float* __restrict__ xdbl) {
  const int i4 = blockIdx.x * 256 + threadIdx.x;  // L*DI/4
  if (i4 < 98304) *(float4*)&xdbl[i4 * 4] = float4{0.f, 0.f, 0.f, 0.f};
  const int l = i4 >> 7;
  const int d = (i4 & 127) * 4;
  float acc[4];
  const float4 cbv = *(const float4*)&cb[d];
  acc[0] = cbv.x; acc[1] = cbv.y; acc[2] = cbv.z; acc[3] = cbv.w;
  #pragma unroll
  for (int j = 0; j < 4; ++j) {
    const int ll = l - 3 + j;
    if (ll >= 0) {
      const ushort4 xv = *(const ushort4*)&xz[(size_t)ll * 1024 + d];
      acc[0] += cw[(d + 0) * 4 + j] * b2f(xv.x);
      acc[1] += cw[(d + 1) * 4 + j] * b2f(xv.y);
      acc[2] += cw[(d + 2) * 4 + j] * b2f(xv.z);
      acc[3] += cw[(d + 3) * 4 + j] * b2f(xv.w);
    }
  }
  ushort4 xo, zo;
  const ushort4 zv = *(const ushort4*)&xz[(size_t)l * 1024 + 512 + d];
  float z0 = b2f(zv.x), z1 = b2f(zv.y), z2 = b2f(zv.z), z3 = b2f(zv.w);
  xo.x = f2b(acc[0] * sigm(acc[0])); xo.y = f2b(acc[1] * sigm(acc[1]));
  xo.z = f2b(acc[2] * sigm(acc[2])); xo.w = f2b(acc[3] * sigm(acc[3]));
  zo.x = f2b(z0 * sigm(z0)); zo.y = f2b(z1 * sigm(z1));
  zo.z = f2b(z2 * sigm(z2)); zo.w = f2b(z3 * sigm(z3));
  *(ushort4*)&xcb[(size_t)l * 512 + d] = xo;
  *(ushort4*)&zsb[(size_t)l * 512 + d] = zo;
}

// ---------------- chunked selective scan; lane-pair state split ----------------
__global__ __launch_bounds__(256) void scan_a_k(const float* __restrict__ xdbl, const u16* __restrict__ xcb,
                                                const float* __restrict__ A_log, const float* __restrict__ dtw,
                                                const float* __restrict__ dtb,
                                                u16* __restrict__ delta,
                                                float* __restrict__ aprod, float* __restrict__ bacc) {
  const int c = blockIdx.x;
  const int t = threadIdx.x;
  const int half = t & 1;
  const int d = blockIdx.y * 128 + (t >> 1);
  const int l0 = c * 64;
  __shared__ float Xs[64][32];  // [lr][0:16)=dr, [16:32)=B
  for (int i = t; i < 2048; i += 256)
    Xs[i >> 5][i & 31] = xdbl[(size_t)(l0 + (i >> 5)) * 48 + (i & 31)];
  __syncthreads();
  float wd[8], Ad[8];
  #pragma unroll
  for (int j = 0; j < 8; ++j) wd[j] = dtw[d * 16 + half * 8 + j];
  const float bd = dtb[d];
  #pragma unroll
  for (int n = 0; n < 8; ++n) Ad[n] = -__expf(A_log[d * 16 + half * 8 + n]);
  float s[8], ap[8];
  #pragma unroll
  for (int n = 0; n < 8; ++n) { s[n] = 0.f; ap[n] = 1.f; }
  #pragma unroll 4
  for (int lr = 0; lr < 64; ++lr) {
    const float4 dr0 = *(const float4*)&Xs[lr][half * 8];
    const float4 dr1 = *(const float4*)&Xs[lr][half * 8 + 4];
    float p0 = dr0.x * wd[0] + dr0.y * wd[1] + dr0.z * wd[2] + dr0.w * wd[3];
    float p1 = dr1.x * wd[4] + dr1.y * wd[5] + dr1.z * wd[6] + dr1.w * wd[7];
    float dot = p0 + p1;
    dot += __shfl_xor(dot, 1);
    const float dl = softplus_fast(dot + bd);
    const int l = l0 + lr;
    if (!half) delta[(size_t)l * 512 + d] = f2b(dl);
    const float du = dl * b2f(xcb[(size_t)l * 512 + d]);
    const float4 B0 = *(const float4*)&Xs[lr][16 + half * 8];
    const float4 B1 = *(const float4*)&Xs[lr][16 + half * 8 + 4];
    const float Bv[8] = {B0.x, B0.y, B0.z, B0.w, B1.x, B1.y, B1.z, B1.w};
    #pragma unroll
    for (int n = 0; n < 8; ++n) {
      const float a = __expf(dl * Ad[n]);
      s[n] = fmaf(a, s[n], du * Bv[n]);
      ap[n] *= a;
    }
  }
  const int base = c * 8192 + d * 16 + half * 8;
  #pragma unroll
  for (int n = 0; n < 8; ++n) { aprod[base + n] = ap[n]; bacc[base + n] = s[n]; }
}

// chunk combine (32 blocks, 128 serial iters, software prefetch)
__global__ __launch_bounds__(256) void scan_b_k(const float* __restrict__ aprod, const float* __restrict__ bacc,
                                                float* __restrict__ sinit) {
  const int st = blockIdx.x * 256 + threadIdx.x;  // 8192 states
  float cur = 0.f;
  float a0 = aprod[st], b0 = bacc[st];
  for (int c = 0; c < 128; ++c) {
    float a1 = 0.f, b1 = 0.f;
    if (c + 1 < 128) {
      a1 = aprod[(size_t)(c + 1) * 8192 + st];
      b1 = bacc[(size_t)(c + 1) * 8192 + st];
    }
    sinit[(size_t)c * 8192 + st] = cur;
    cur = fmaf(a0, cur, b0);
    a0 = a1; b0 = b1;
  }
}

__global__ __launch_bounds__(256) void scan_c_k(const float* __restrict__ xdbl, const u16* __restrict__ xcb,
                                                const u16* __restrict__ zsb, const float* __restrict__ A_log,
                                                const u16* __restrict__ delta,
                                                const float* __restrict__ sinit,
                                                const float* __restrict__ Dp, u16* __restrict__ yv) {
  const int c = blockIdx.x;
  const int t = threadIdx.x;
  const int half = t & 1;
  const int d = blockIdx.y * 128 + (t >> 1);
  const int l0 = c * 64;
  __shared__ float Xs[64][32];  // [lr][0:16)=B, [16:32)=C
  for (int i = t; i < 2048; i += 256)
    Xs[i >> 5][i & 31] = xdbl[(size_t)(l0 + (i >> 5)) * 48 + 16 + (i & 31)];
  __syncthreads();
  float Ad[8];
  #pragma unroll
  for (int n = 0; n < 8; ++n) Ad[n] = -__expf(A_log[d * 16 + half * 8 + n]);
  float s[8];
  const int base = c * 8192 + d * 16 + half * 8;
  #pragma unroll
  for (int n = 0; n < 8; ++n) s[n] = sinit[base + n];
  const float Dd = Dp[d];
  #pragma unroll 4
  for (int lr = 0; lr < 64; ++lr) {
    const int l = l0 + lr;
    const float dl = b2f(delta[(size_t)l * 512 + d]);
    const float xv = b2f(xcb[(size_t)l * 512 + d]);
    const float zs = b2f(zsb[(size_t)l * 512 + d]);
    const float du = dl * xv;
    const float4 B0 = *(const float4*)&Xs[lr][half * 8];
    const float4 B1 = *(const float4*)&Xs[lr][half * 8 + 4];
    const float4 C0 = *(const float4*)&Xs[lr][16 + half * 8];
    const float4 C1 = *(const float4*)&Xs[lr][16 + half * 8 + 4];
    const float Bv[8] = {B0.x, B0.y, B0.z, B0.w, B1.x, B1.y, B1.z, B1.w};
    const float Cv[8] = {C0.x, C0.y, C0.z, C0.w, C1.x, C1.y, C1.z, C1.w};
    float y = 0.f;
    #pragma unroll
    for (int n = 0; n < 8; ++n) {
      const float a = __expf(dl * Ad[n]);
      s[n] = fmaf(a, s[n], du * Bv[n]);
      y = fmaf(s[n], Cv[n], y);
    }
    y += __shfl_xor(y, 1);
    if (!half) yv[(size_t)l * 512 + d] = f2b((y + xv * Dd) * zs);
  }
}

extern "C" void kernel_launch(void* const* d_in, const int* in_sizes, int n_in,
                              void* d_out, int out_size, void* d_ws, size_t ws_size,
                              hipStream_t stream) {
  const float* x        = (const float*)d_in[0];
  const float* lin_w    = (const float*)d_in[1];
  const float* in_proj  = (const float*)d_in[2];
  const float* conv_w   = (const float*)d_in[3];
  const float* conv_b   = (const float*)d_in[4];
  const float* x_proj   = (const float*)d_in[5];
  const float* dt_w     = (const float*)d_in[6];
  const float* dt_b     = (const float*)d_in[7];
  const float* A_log    = (const float*)d_in[8];
  const float* D_param  = (const float*)d_in[9];
  const float* out_proj = (const float*)d_in[10];
  const float* gate_w   = (const float*)d_in[11];
  const float* gproj    = (const float*)d_in[12];
  const float* uproj    = (const float*)d_in[13];
  const float* dproj    = (const float*)d_in[14];
  const float* rms_a_w  = (const float*)d_in[15];
  const float* rms_f_w  = (const float*)d_in[16];
  const float* head_w1  = (const float*)d_in[17];
  const float* head_w2  = (const float*)d_in[18];

  char* p = (char*)d_ws;
  auto alloc = [&](size_t bytes) -> char* {
    char* r = p;
    p += (bytes + 255) & ~(size_t)255;
    return r;
  };

  // bf16 weight pool
  u16* lin_b  = (u16*)alloc(65536 * 2);
  u16* ipw_b  = (u16*)alloc((size_t)2097152 * 2);
  u16* xpw_b  = (u16*)alloc((size_t)196608 * 2);
  u16* opw_b  = (u16*)alloc((size_t)1048576 * 2);
  u16* gupw_b = (u16*)alloc((size_t)8388608 * 2);  // 16-wide gu interleave, expert-grouped
  u16* dpw_b  = (u16*)alloc((size_t)4194304 * 2);
  u16* hw1_b  = (u16*)alloc(65536 * 2);
  u16* hw2_b  = (u16*)alloc(8192 * 2);

  // activations
  u16* xT     = (u16*)alloc((size_t)kL * kDIM * 2);
  float* h    = (float*)alloc((size_t)kL * kDIM * 4);
  u16* hn     = (u16*)alloc((size_t)kL * kDIM * 2);
  u16* hb2    = (u16*)alloc((size_t)kL * kDIM * 2);
  float* xdbl = (float*)alloc((size_t)kL * 48 * 4);
  u16* fb     = (u16*)alloc((size_t)kL * kDIM * 2);
  u16* h2b    = (u16*)alloc((size_t)kL * kDIM * 2);
  u16* xz     = (u16*)alloc((size_t)kL * 1024 * 2);
  u16* xcb    = (u16*)alloc((size_t)kL * kDI * 2);
  u16* zsb    = (u16*)alloc((size_t)kL * kDI * 2);
  u16* yv     = (u16*)alloc((size_t)kL * kDI * 2);
  u16* delta  = (u16*)alloc((size_t)kL * kDI * 2);
  float* aprod = (float*)alloc((size_t)128 * 8192 * 4);
  float* bacc  = (float*)alloc((size_t)128 * 8192 * 4);
  float* sinit = (float*)alloc((size_t)128 * 8192 * 4);
  float* hpart = (float*)alloc((size_t)4 * kL * kDIM * 4);

  if ((size_t)(p - (char*)d_ws) > ws_size) return;  // fail loudly

  // ---- weight conversion ----
  Cvt2 dd;
  int seg = 0, blk = 0;
  auto add = [&](const float* s, u16* d, int n, int mode) {
    dd.s[seg] = s; dd.d[seg] = d; dd.n[seg] = n; dd.mode[seg] = mode;
    dd.bstart[seg] = blk;
    blk += (n + 4095) / 4096;
    ++seg;
  };
  add(lin_w, lin_b, 65536, 0);
  add(in_proj, ipw_b, 2097152, 0);
  add(x_proj, xpw_b, 196608, 0);
  add(out_proj, opw_b, 1048576, 0);
  add(head_w1, hw1_b, 65536, 0);
  add(head_w2, hw2_b, 8192, 0);
  for (int i = 0; i < kNB; ++i) {
    add(gproj + (size_t)i * 524288, gupw_b + (size_t)i * 1048576, 524288, 1);
    add(uproj + (size_t)i * 524288, gupw_b + (size_t)i * 1048576 + 4096, 524288, 1);
  }
  add(dproj, dpw_b, 4194304, 2);
  dd.nseg = seg;
  dd.bstart[seg] = blk;
  cvt2_k<<<blk, 256, 0, stream>>>(dd);
  transpose_x_k<<<dim3(kL / 32, kDIM / 32), dim3(32, 8), 0, stream>>>(x, xT);

  // h = xT @ lin_w^T
  gemm_t<64, 128, 2, 4, 2, 0><<<dim3(128, 2, 1), 256, 0, stream>>>(
      xT, 256, lin_b, 256, h, 256, 256, 256, 0);
  rms_a_k<<<kL, 256, 0, stream>>>(h, rms_a_w, hn);

  for (int i = 0; i < kNB; ++i) {
    // in_proj: N=1024, K=256 -> xz bf16
    gemm_t<128, 128, 4, 4, 2, 2><<<dim3(64, 8, 1), 256, 0, stream>>>(
        hn, 256, ipw_b + (size_t)i * 262144, 256, xz, 1024, 1024, 256, 0);
    conv_silu_k<<<kL * kDI / 1024, 256, 0, stream>>>(xz, conv_w + (size_t)i * 2048,
                                                     conv_b + (size_t)i * 512, xcb, zsb, xdbl);
    // xdbl: N=48, K=512, split-K=8 atomic (xdbl zeroed by conv kernel)
    gemm_t<128, 48, 2, 3, 1, 4><<<dim3(64, 1, 8), 256, 0, stream>>>(
        xcb, 512, xpw_b + (size_t)i * 24576, 512, xdbl, 48, 48, 512, 0);
    scan_a_k<<<dim3(128, 4), 256, 0, stream>>>(xdbl, xcb, A_log + (size_t)i * 8192,
                                               dt_w + (size_t)i * 8192, dt_b + (size_t)i * 512,
                                               delta, aprod, bacc);
    scan_b_k<<<32, 256, 0, stream>>>(aprod, bacc, sinit);
    scan_c_k<<<dim3(128, 4), 256, 0, stream>>>(xdbl, xcb, zsb, A_log + (size_t)i * 8192,
                                               delta, sinit, D_param + (size_t)i * 512, yv);
    // out_proj: split-K=4 -> 4 partial buffers (reduced in mega)
    gemm_t<128, 128, 4, 4, 2, 5><<<dim3(64, 2, 4), 256, 0, stream>>>(
        yv, 512, opw_b + (size_t)i * 131072, 512, hpart, 256, 256, 512, 2097152);
    // fused MoE (router + gu + GLU + dproj + rms_f + rms_a)
    moe_mega_k<<<256, 512, 0, stream>>>(h, hpart, gate_w + (size_t)i * 1024,
                                        gupw_b + (size_t)i * 1048576, dpw_b + (size_t)i * 524288,
                                        rms_f_w, rms_a_w, hb2, hn);
  }

  // head: lin -> silu(head1) -> head2 + sigmoid-transpose fused
  gemm_t<64, 128, 2, 4, 2, 2><<<dim3(128, 2, 1), 256, 0, stream>>>(
      hb2, 256, lin_b, 256, h2b, 256, 256, 256, 0);
  gemm_t<64, 128, 2, 4, 2, 3><<<dim3(128, 2, 1), 256, 0, stream>>>(
      h2b, 256, hw1_b, 256, fb, 256, 256, 256, 0);
  gemm_t<64, 128, 2, 4, 2, 7><<<dim3(128, 1, 1), 256, 0, stream>>>(
      fb, 256, hw2_b, 256, (float*)d_out, 32, 32, 256, 0);
}